// Round 2
// baseline (1765.750 us; speedup 1.0000x reference)
//
#include <hip/hip_runtime.h>

#define N_NODES 50000

typedef __bf16 bf16x8 __attribute__((ext_vector_type(8)));
typedef float f32x4 __attribute__((ext_vector_type(4)));

union U16x8 { uint4 v; unsigned short u[8]; bf16x8 b; };

__device__ __forceinline__ float b2f(unsigned short h){
  unsigned int u = ((unsigned int)h) << 16;
  return __builtin_bit_cast(float, u);
}
__device__ __forceinline__ unsigned short f2b(float x){
  unsigned int u = __builtin_bit_cast(unsigned int, x);
  u = u + 0x7FFFu + ((u >> 16) & 1u);
  return (unsigned short)(u >> 16);
}
__device__ __forceinline__ float sigm(float x){ return 1.0f / (1.0f + __expf(-x)); }
__device__ __forceinline__ float tanh_(float x){ return 1.0f - 2.0f / (1.0f + __expf(2.0f * x)); }

// 8 consecutive f32 -> bf16x8 (round-to-nearest-even), hi only
__device__ __forceinline__ bf16x8 load8_bf16(const float* p){
  float4 a = *(const float4*)p; float4 c = *(const float4*)(p + 4);
  U16x8 r;
  r.u[0]=f2b(a.x); r.u[1]=f2b(a.y); r.u[2]=f2b(a.z); r.u[3]=f2b(a.w);
  r.u[4]=f2b(c.x); r.u[5]=f2b(c.y); r.u[6]=f2b(c.z); r.u[7]=f2b(c.w);
  return r.b;
}
// 8 consecutive f32 -> hi/lo bf16x8 pair (x ~= hi + lo)
__device__ __forceinline__ void load8_hilo(const float* p, bf16x8& H, bf16x8& L){
  float4 a = *(const float4*)p; float4 c = *(const float4*)(p + 4);
  float v[8] = {a.x, a.y, a.z, a.w, c.x, c.y, c.z, c.w};
  U16x8 h_, l_;
  #pragma unroll
  for (int j = 0; j < 8; j++){
    unsigned short hb = f2b(v[j]); h_.u[j] = hb; l_.u[j] = f2b(v[j] - b2f(hb));
  }
  H = h_.b; L = l_.b;
}

// ---------------------------------------------------------------------------
// Layer 1: d=11 LSTM aggregation, VALU fp32. One thread per node.
// ---------------------------------------------------------------------------
__global__ __launch_bounds__(256) void l1_kernel(
    const float* __restrict__ x, const int* __restrict__ nbr,
    const float* __restrict__ Wih, const float* __restrict__ Whh,
    const float* __restrict__ bih, const float* __restrict__ bhh,
    const float* __restrict__ Ws,  const float* __restrict__ bs,
    const float* __restrict__ Wn,  float* __restrict__ out)
{
  __shared__ float sWih[44*11], sWhh[44*11], sB[44], sWs[64*11], sWn[64*11], sBs[64];
  const int tid = threadIdx.x;
  for (int i = tid; i < 484; i += 256){ sWih[i] = Wih[i]; sWhh[i] = Whh[i]; }
  for (int i = tid; i < 704; i += 256){ sWs[i]  = Ws[i];  sWn[i]  = Wn[i]; }
  for (int i = tid; i < 44;  i += 256){ sB[i]   = bih[i] + bhh[i]; }
  for (int i = tid; i < 64;  i += 256){ sBs[i]  = bs[i]; }
  __syncthreads();

  const int node = blockIdx.x * 256 + tid;
  if (node >= N_NODES) return;

  float h[11], c[11], hn[11], m[11];
  #pragma unroll
  for (int j = 0; j < 11; j++){ h[j] = 0.f; c[j] = 0.f; }

  for (int t = 0; t < 16; t++){
    const int gn = nbr[node * 16 + t];
    #pragma unroll
    for (int j = 0; j < 11; j++) m[j] = x[gn * 11 + j];
    #pragma unroll
    for (int u = 0; u < 11; u++){
      float ai = sB[u], af = sB[11+u], ag = sB[22+u], ao = sB[33+u];
      #pragma unroll
      for (int k = 0; k < 11; k++){
        ai += m[k]*sWih[u*11+k]      + h[k]*sWhh[u*11+k];
        af += m[k]*sWih[(11+u)*11+k] + h[k]*sWhh[(11+u)*11+k];
        ag += m[k]*sWih[(22+u)*11+k] + h[k]*sWhh[(22+u)*11+k];
        ao += m[k]*sWih[(33+u)*11+k] + h[k]*sWhh[(33+u)*11+k];
      }
      c[u]  = sigm(af) * c[u] + sigm(ai) * tanh_(ag);
      hn[u] = sigm(ao) * tanh_(c[u]);
    }
    #pragma unroll
    for (int j = 0; j < 11; j++) h[j] = hn[j];
  }

  float xs[11];
  #pragma unroll
  for (int j = 0; j < 11; j++) xs[j] = x[node * 11 + j];
  for (int uo = 0; uo < 64; uo++){
    float a = sBs[uo];
    #pragma unroll
    for (int k = 0; k < 11; k++) a += xs[k]*sWs[uo*11+k] + h[k]*sWn[uo*11+k];
    out[(long)node * 64 + uo] = fmaxf(a, 0.f);
  }
}

// ---------------------------------------------------------------------------
// Layers 2/3/4: d=64 LSTM aggregation via MFMA 16x16x32 bf16, hi/lo split on A.
// Block: 16 nodes, 256 threads (4 waves). Wave w owns hidden units u=16w..16w+15
// for all 4 gates (gate t4 = col tile). Weights live as bf16 B-frags in VGPRs.
// mode 0: out[n*64+u] = relu(hself@WsT + bs + hK@WnT)   (fp32 table)
// mode 1: out[n]      = hself@WsT + bs + hK@WnT  (o=1)  (fp32 logits)
// ---------------------------------------------------------------------------
__global__ __launch_bounds__(256, 3) void sage64_kernel(
    const float* __restrict__ in, const int* __restrict__ nbr,
    const float* __restrict__ Wih, const float* __restrict__ Whh,
    const float* __restrict__ bih, const float* __restrict__ bhh,
    const float* __restrict__ Ws,  const float* __restrict__ bs,
    const float* __restrict__ Wn,
    float* __restrict__ out, int mode)
{
  // frag buffers: [dbuf][hi/lo][kc][lane] ; each uint4 = 8 bf16 (one A-frag slot)
  __shared__ uint4 mfrag[2][2][2][64];
  __shared__ uint4 hfrag[2][2][2][64];
  __shared__ int nbr_s[16 * 17];

  const int tid  = threadIdx.x;
  const int wave = tid >> 6, lane = tid & 63;
  const int n16  = lane & 15, q = lane >> 4;
  const int nb0  = blockIdx.x * 16;

  // stage neighbor table (padded stride 17)
  { const int nd = tid >> 4, t = tid & 15;
    nbr_s[nd * 17 + t] = nbr[(nb0 + nd) * 16 + t]; }

  // zero initial h frags (buffer 0 = 256 uint4, one per thread)
  ((uint4*)hfrag)[tid] = make_uint4(0u, 0u, 0u, 0u);

  // gather m_0 into mfrag[0]: thread = (node nd, k-quad k0)
  {
    const int nd = tid >> 4, k0 = (tid & 15) * 4;
    const int gn = nbr[(nb0 + nd) * 16 + 0];
    float4 v = *(const float4*)(in + (long)gn * 64 + k0);
    unsigned short h0 = f2b(v.x), h1 = f2b(v.y), h2 = f2b(v.z), h3 = f2b(v.w);
    unsigned short l0 = f2b(v.x - b2f(h0)), l1 = f2b(v.y - b2f(h1));
    unsigned short l2 = f2b(v.z - b2f(h2)), l3 = f2b(v.w - b2f(h3));
    const int kc = k0 >> 5, qq = (k0 >> 3) & 3, lp = nd + 16 * qq, half = (k0 & 7) >> 2;
    ((uint2*)&mfrag[0][0][kc][lp])[half] = make_uint2((unsigned)h0 | ((unsigned)h1 << 16),
                                                     (unsigned)h2 | ((unsigned)h3 << 16));
    ((uint2*)&mfrag[0][1][kc][lp])[half] = make_uint2((unsigned)l0 | ((unsigned)l1 << 16),
                                                     (unsigned)l2 | ((unsigned)l3 << 16));
  }

  // B-fragments (weights) resident in VGPRs: lane converts 8 f32 of row ct*16+n16
  bf16x8 wih_f[4][2], whh_f[4][2];
  #pragma unroll
  for (int t4 = 0; t4 < 4; t4++){
    const int row = t4 * 64 + wave * 16 + n16;
    #pragma unroll
    for (int kc = 0; kc < 2; kc++){
      wih_f[t4][kc] = load8_bf16(Wih + row * 64 + kc * 32 + q * 8);
      whh_f[t4][kc] = load8_bf16(Whh + row * 64 + kc * 32 + q * 8);
    }
  }
  const int u_ = wave * 16 + n16;
  float b4[4];
  #pragma unroll
  for (int t4 = 0; t4 < 4; t4++) b4[t4] = bih[t4 * 64 + u_] + bhh[t4 * 64 + u_];

  float c4[4] = {0.f, 0.f, 0.f, 0.f};
  const int kch = u_ >> 5, qh = (u_ >> 3) & 3, jh = u_ & 7;

  __syncthreads();

  for (int t = 0; t < 16; t++){
    const int db = t & 1, nbuf = db ^ 1;

    // read A-frags (m_t and h_t) in frag order: consecutive 16B per lane
    bf16x8 mh[2], ml[2], hh[2], hl[2];
    #pragma unroll
    for (int kc = 0; kc < 2; kc++){
      U16x8 a; a.v = mfrag[db][0][kc][lane]; mh[kc] = a.b;
      U16x8 b_; b_.v = mfrag[db][1][kc][lane]; ml[kc] = b_.b;
      U16x8 cc; cc.v = hfrag[db][0][kc][lane]; hh[kc] = cc.b;
      U16x8 d_; d_.v = hfrag[db][1][kc][lane]; hl[kc] = d_.b;
    }

    // issue gather for m_{t+1} now; consume after MFMAs (latency overlap)
    float4 gv = make_float4(0.f, 0.f, 0.f, 0.f);
    const int nd = tid >> 4, k0 = (tid & 15) * 4;
    if (t < 15){
      const int gn = nbr_s[nd * 17 + t + 1];
      gv = *(const float4*)(in + (long)gn * 64 + k0);
    }

    // G = bias + m@WihT + h@WhhT  (hi/lo split on A side)
    f32x4 acc[4];
    #pragma unroll
    for (int t4 = 0; t4 < 4; t4++){ f32x4 av = {b4[t4], b4[t4], b4[t4], b4[t4]}; acc[t4] = av; }
    #pragma unroll
    for (int kc = 0; kc < 2; kc++){
      #pragma unroll
      for (int t4 = 0; t4 < 4; t4++)
        acc[t4] = __builtin_amdgcn_mfma_f32_16x16x32_bf16(mh[kc], wih_f[t4][kc], acc[t4], 0, 0, 0);
      #pragma unroll
      for (int t4 = 0; t4 < 4; t4++)
        acc[t4] = __builtin_amdgcn_mfma_f32_16x16x32_bf16(ml[kc], wih_f[t4][kc], acc[t4], 0, 0, 0);
      #pragma unroll
      for (int t4 = 0; t4 < 4; t4++)
        acc[t4] = __builtin_amdgcn_mfma_f32_16x16x32_bf16(hh[kc], whh_f[t4][kc], acc[t4], 0, 0, 0);
      #pragma unroll
      for (int t4 = 0; t4 < 4; t4++)
        acc[t4] = __builtin_amdgcn_mfma_f32_16x16x32_bf16(hl[kc], whh_f[t4][kc], acc[t4], 0, 0, 0);
    }

    // gates: lane holds i/f/g/o of unit u_ for nodes q*4+r (C row = q*4+reg)
    #pragma unroll
    for (int r = 0; r < 4; r++){
      const float iv = sigm(acc[0][r]);
      const float fv = sigm(acc[1][r]);
      const float gg = tanh_(acc[2][r]);
      const float ov = sigm(acc[3][r]);
      c4[r] = fv * c4[r] + iv * gg;
      const float hv = ov * tanh_(c4[r]);
      const unsigned short hb = f2b(hv);
      const unsigned short lb = f2b(hv - b2f(hb));
      const int lp = (q * 4 + r) + 16 * qh;
      ((unsigned short*)&hfrag[nbuf][0][kch][lp])[jh] = hb;
      ((unsigned short*)&hfrag[nbuf][1][kch][lp])[jh] = lb;
    }

    // write gathered m_{t+1} frags
    if (t < 15){
      unsigned short h0 = f2b(gv.x), h1 = f2b(gv.y), h2 = f2b(gv.z), h3 = f2b(gv.w);
      unsigned short l0 = f2b(gv.x - b2f(h0)), l1 = f2b(gv.y - b2f(h1));
      unsigned short l2 = f2b(gv.z - b2f(h2)), l3 = f2b(gv.w - b2f(h3));
      const int kc = k0 >> 5, qq = (k0 >> 3) & 3, lp = nd + 16 * qq, half = (k0 & 7) >> 2;
      ((uint2*)&mfrag[nbuf][0][kc][lp])[half] = make_uint2((unsigned)h0 | ((unsigned)h1 << 16),
                                                          (unsigned)h2 | ((unsigned)h3 << 16));
      ((uint2*)&mfrag[nbuf][1][kc][lp])[half] = make_uint2((unsigned)l0 | ((unsigned)l1 << 16),
                                                          (unsigned)l2 | ((unsigned)l3 << 16));
    }
    __syncthreads();
  }

  // ---- epilogue: out = hself@WsT + bs + hK@WnT ----
  bf16x8 sh[2], sl[2];
  #pragma unroll
  for (int kc = 0; kc < 2; kc++)
    load8_hilo(in + (long)(nb0 + n16) * 64 + kc * 32 + q * 8, sh[kc], sl[kc]);

  bf16x8 kh[2], kl[2];   // final h (t=15 wrote buffer 0)
  #pragma unroll
  for (int kc = 0; kc < 2; kc++){
    U16x8 a; a.v = hfrag[0][0][kc][lane]; kh[kc] = a.b;
    U16x8 b_; b_.v = hfrag[0][1][kc][lane]; kl[kc] = b_.b;
  }

  if (mode == 0){
    bf16x8 ws_f[2], wn_f[2];
    #pragma unroll
    for (int kc = 0; kc < 2; kc++){
      ws_f[kc] = load8_bf16(Ws + (wave * 16 + n16) * 64 + kc * 32 + q * 8);
      wn_f[kc] = load8_bf16(Wn + (wave * 16 + n16) * 64 + kc * 32 + q * 8);
    }
    f32x4 e = {0.f, 0.f, 0.f, 0.f};
    #pragma unroll
    for (int kc = 0; kc < 2; kc++){
      e = __builtin_amdgcn_mfma_f32_16x16x32_bf16(sh[kc], ws_f[kc], e, 0, 0, 0);
      e = __builtin_amdgcn_mfma_f32_16x16x32_bf16(sl[kc], ws_f[kc], e, 0, 0, 0);
      e = __builtin_amdgcn_mfma_f32_16x16x32_bf16(kh[kc], wn_f[kc], e, 0, 0, 0);
      e = __builtin_amdgcn_mfma_f32_16x16x32_bf16(kl[kc], wn_f[kc], e, 0, 0, 0);
    }
    const int col = wave * 16 + n16;
    const float bsv = bs[col];
    #pragma unroll
    for (int r = 0; r < 4; r++)
      out[(long)(nb0 + q * 4 + r) * 64 + col] = fmaxf(e[r] + bsv, 0.f);
  } else {
    if (wave == 0){
      bf16x8 ws_f[2], wn_f[2];
      #pragma unroll
      for (int kc = 0; kc < 2; kc++){
        U16x8 a, b_;
        a.v = make_uint4(0u,0u,0u,0u); b_.v = make_uint4(0u,0u,0u,0u);
        if (n16 == 0){
          a.b  = load8_bf16(Ws + kc * 32 + q * 8);
          b_.b = load8_bf16(Wn + kc * 32 + q * 8);
        }
        ws_f[kc] = a.b; wn_f[kc] = b_.b;
      }
      f32x4 e = {0.f, 0.f, 0.f, 0.f};
      #pragma unroll
      for (int kc = 0; kc < 2; kc++){
        e = __builtin_amdgcn_mfma_f32_16x16x32_bf16(sh[kc], ws_f[kc], e, 0, 0, 0);
        e = __builtin_amdgcn_mfma_f32_16x16x32_bf16(sl[kc], ws_f[kc], e, 0, 0, 0);
        e = __builtin_amdgcn_mfma_f32_16x16x32_bf16(kh[kc], wn_f[kc], e, 0, 0, 0);
        e = __builtin_amdgcn_mfma_f32_16x16x32_bf16(kl[kc], wn_f[kc], e, 0, 0, 0);
      }
      if (n16 == 0){
        const float bsv = bs[0];
        #pragma unroll
        for (int r = 0; r < 4; r++)
          out[nb0 + q * 4 + r] = e[r] + bsv;
      }
    }
  }
}

// ---------------------------------------------------------------------------
// GRU cell (one shot): h = (1-z)*n + z*prev. MFMA, no LDS.
// ---------------------------------------------------------------------------
__global__ __launch_bounds__(256) void gru_kernel(
    const float* __restrict__ h3, const float* __restrict__ prev,
    const float* __restrict__ gWih, const float* __restrict__ gWhh,
    const float* __restrict__ gbih, const float* __restrict__ gbhh,
    float* __restrict__ out)
{
  const int tid = threadIdx.x, wave = tid >> 6, lane = tid & 63;
  const int n16 = lane & 15, q = lane >> 4;
  const int nb0 = blockIdx.x * 16;
  const int u_ = wave * 16 + n16;

  bf16x8 ah[2], al[2], ap[2];
  #pragma unroll
  for (int kc = 0; kc < 2; kc++){
    load8_hilo(h3 + (long)(nb0 + n16) * 64 + kc * 32 + q * 8, ah[kc], al[kc]);
    ap[kc] = load8_bf16(prev + (long)(nb0 + n16) * 64 + kc * 32 + q * 8);
  }

  bf16x8 wi_f[3][2], wh_f[3][2];
  #pragma unroll
  for (int g = 0; g < 3; g++){
    const int row = g * 64 + wave * 16 + n16;
    #pragma unroll
    for (int kc = 0; kc < 2; kc++){
      wi_f[g][kc] = load8_bf16(gWih + row * 64 + kc * 32 + q * 8);
      wh_f[g][kc] = load8_bf16(gWhh + row * 64 + kc * 32 + q * 8);
    }
  }

  f32x4 gi[3], gh[3];
  #pragma unroll
  for (int g = 0; g < 3; g++){
    const float bi = gbih[g * 64 + u_], bh = gbhh[g * 64 + u_];
    f32x4 vi = {bi, bi, bi, bi}; gi[g] = vi;
    f32x4 vh = {bh, bh, bh, bh}; gh[g] = vh;
  }
  #pragma unroll
  for (int kc = 0; kc < 2; kc++){
    #pragma unroll
    for (int g = 0; g < 3; g++)
      gi[g] = __builtin_amdgcn_mfma_f32_16x16x32_bf16(ah[kc], wi_f[g][kc], gi[g], 0, 0, 0);
    #pragma unroll
    for (int g = 0; g < 3; g++)
      gi[g] = __builtin_amdgcn_mfma_f32_16x16x32_bf16(al[kc], wi_f[g][kc], gi[g], 0, 0, 0);
    #pragma unroll
    for (int g = 0; g < 3; g++)
      gh[g] = __builtin_amdgcn_mfma_f32_16x16x32_bf16(ap[kc], wh_f[g][kc], gh[g], 0, 0, 0);
  }

  #pragma unroll
  for (int r = 0; r < 4; r++){
    const long node = nb0 + q * 4 + r;
    const float rv = sigm(gi[0][r] + gh[0][r]);
    const float zv = sigm(gi[1][r] + gh[1][r]);
    const float nv = tanh_(gi[2][r] + rv * gh[2][r]);
    const float hp = prev[node * 64 + u_];
    out[node * 64 + u_] = (1.f - zv) * nv + zv * hp;
  }
}

// ---------------------------------------------------------------------------
extern "C" void kernel_launch(void* const* d_in, const int* in_sizes, int n_in,
                              void* d_out, int out_size, void* d_ws, size_t ws_size,
                              hipStream_t stream)
{
  (void)in_sizes; (void)n_in; (void)out_size; (void)ws_size;
  const float* x    = (const float*)d_in[0];
  const int*   nbr  = (const int*)d_in[1];
  const float* prev = (const float*)d_in[2];
  auto W = [&](int i){ return (const float*)d_in[i]; };

  float* bufA = (float*)d_ws;                      // 50000*64 fp32 = 12.8 MB
  float* bufB = bufA + (size_t)N_NODES * 64;       // second 12.8 MB

  // layer 1 (d=11, VALU): x -> bufA (=h1)
  l1_kernel<<<(N_NODES + 255) / 256, 256, 0, stream>>>(
      x, nbr, W(3), W(4), W(5), W(6), W(7), W(8), W(9), bufA);
  // layer 2: bufA -> bufB (=h2)
  sage64_kernel<<<N_NODES / 16, 256, 0, stream>>>(
      bufA, nbr, W(10), W(11), W(12), W(13), W(14), W(15), W(16), bufB, 0);
  // layer 3: bufB -> bufA (=h3)
  sage64_kernel<<<N_NODES / 16, 256, 0, stream>>>(
      bufB, nbr, W(17), W(18), W(19), W(20), W(21), W(22), W(23), bufA, 0);
  // GRU: (h3=bufA, prev) -> bufB (=h)
  gru_kernel<<<N_NODES / 16, 256, 0, stream>>>(
      bufA, prev, W(31), W(32), W(33), W(34), bufB);
  // layer 4 (o=1): bufB -> d_out (fp32 logits)
  sage64_kernel<<<N_NODES / 16, 256, 0, stream>>>(
      bufB, nbr, W(24), W(25), W(26), W(27), W(28), W(29), W(30),
      (float*)d_out, 1);
}

// Round 3
// 832.995 us; speedup vs baseline: 2.1198x; 2.1198x over previous
//
#include <hip/hip_runtime.h>

#define N_NODES 50000

typedef __bf16 bf16x8 __attribute__((ext_vector_type(8)));
typedef float f32x4 __attribute__((ext_vector_type(4)));

union U16x8 { uint4 v; unsigned short u[8]; bf16x8 b; };

__device__ __forceinline__ float b2f(unsigned short h){
  unsigned int u = ((unsigned int)h) << 16;
  return __builtin_bit_cast(float, u);
}
__device__ __forceinline__ unsigned short f2b(float x){
  unsigned int u = __builtin_bit_cast(unsigned int, x);
  u = u + 0x7FFFu + ((u >> 16) & 1u);
  return (unsigned short)(u >> 16);
}
__device__ __forceinline__ float sigm(float x){ return 1.0f / (1.0f + __expf(-x)); }
__device__ __forceinline__ float tanh_(float x){ return 1.0f - 2.0f / (1.0f + __expf(2.0f * x)); }

// 8 consecutive f32 -> bf16x8 (round-to-nearest-even), hi only
__device__ __forceinline__ bf16x8 load8_bf16(const float* p){
  float4 a = *(const float4*)p; float4 c = *(const float4*)(p + 4);
  U16x8 r;
  r.u[0]=f2b(a.x); r.u[1]=f2b(a.y); r.u[2]=f2b(a.z); r.u[3]=f2b(a.w);
  r.u[4]=f2b(c.x); r.u[5]=f2b(c.y); r.u[6]=f2b(c.z); r.u[7]=f2b(c.w);
  return r.b;
}
// 8 consecutive f32 -> hi/lo bf16x8 pair (x ~= hi + lo)
__device__ __forceinline__ void load8_hilo(const float* p, bf16x8& H, bf16x8& L){
  float4 a = *(const float4*)p; float4 c = *(const float4*)(p + 4);
  float v[8] = {a.x, a.y, a.z, a.w, c.x, c.y, c.z, c.w};
  U16x8 h_, l_;
  #pragma unroll
  for (int j = 0; j < 8; j++){
    unsigned short hb = f2b(v[j]); h_.u[j] = hb; l_.u[j] = f2b(v[j] - b2f(hb));
  }
  H = h_.b; L = l_.b;
}

// ---------------------------------------------------------------------------
// Layer 1 (d=11) via MFMA: block = 16 nodes, 4 waves. K=32 operand packs
// [m (k0..10) ; h (k16..26)]. Wave g computes gate g (cols = 16 units, 11 valid).
// All 256 (node,t) neighbor rows gathered upfront into LDS hi/lo fragments.
// c-state lives in threads tid<176 (nd=tid&15, u=tid>>4).
// Epilogue: out[n][0..63] = relu(x_self@WsT + bs + hK@WnT), col tile = wave.
// ---------------------------------------------------------------------------
__global__ __launch_bounds__(256) void l1_kernel(
    const float* __restrict__ x, const int* __restrict__ nbr,
    const float* __restrict__ Wih, const float* __restrict__ Whh,
    const float* __restrict__ bih, const float* __restrict__ bhh,
    const float* __restrict__ Ws,  const float* __restrict__ bs,
    const float* __restrict__ Wn,  float* __restrict__ out)
{
  // mbuf[t][hl][nd][24 u16]  (pad 16->24: 48B rows, 2-way banks = free, 16B aligned)
  __shared__ unsigned short mbuf[16][2][16][24];   // 24.6 KB
  __shared__ unsigned short hbuf[2][2][16][24];    // 3 KB
  __shared__ float pre[4][16][17];                 // 4.4 KB  [gate][node][unit]

  const int tid  = threadIdx.x;
  const int wave = tid >> 6, lane = tid & 63;
  const int n16  = lane & 15, q = lane >> 4;
  const int nb0  = blockIdx.x * 16;

  // ---- zero hbuf (both buffers: initial h=0 and unit pads) ----
  { unsigned int* p = (unsigned int*)hbuf;         // 1536 u16 = 768 uints
    for (int i = tid; i < 768; i += 256) p[i] = 0u; }

  // ---- gather all 16x16 neighbor rows, convert hi/lo, stage to LDS ----
  {
    const int nd = tid >> 4, t = tid & 15;
    const int gn = nbr[(nb0 + nd) * 16 + t];
    const float* row = x + (long)gn * 11;
    float v[16];
    #pragma unroll
    for (int j = 0; j < 11; j++) v[j] = row[j];
    #pragma unroll
    for (int j = 11; j < 16; j++) v[j] = 0.f;
    #pragma unroll
    for (int j = 0; j < 16; j++){
      unsigned short hb = f2b(v[j]);
      mbuf[t][0][nd][j] = hb;
      mbuf[t][1][nd][j] = f2b(v[j] - b2f(hb));
    }
  }

  // ---- B-fragment (combined [Wih | Whh] for gate=wave), bf16, resident ----
  // lane (n16=u, q): k=q*8+j ; q<2 -> Wih[g*11+u][k], q>=2 -> Whh[g*11+u][k-16]
  bf16x8 wf;
  {
    const int u = n16;
    const float* src = (q < 2) ? (Wih + (wave * 11 + u) * 11)
                               : (Whh + (wave * 11 + u) * 11);
    const int kb = (q & 1) * 8;    // k within the 16-wide half
    U16x8 a;
    #pragma unroll
    for (int j = 0; j < 8; j++){
      const int k = kb + j;
      float v = (u < 11 && k < 11) ? src[k] : 0.f;
      a.u[j] = f2b(v);
    }
    wf = a.b;
  }
  const float bg = (n16 < 11) ? (bih[wave * 11 + n16] + bhh[wave * 11 + n16]) : 0.f;

  // c-state owner threads
  const int nd_o = tid & 15, u_o = tid >> 4;     // valid when tid<176
  float c_o = 0.f;

  __syncthreads();

  // ---- 16-step LSTM recurrence ----
  for (int t = 0; t < 16; t++){
    const int db = t & 1, nb = db ^ 1;

    // A-frag hi/lo: q<2 from mbuf[t], q>=2 from hbuf[db]; hl stride = 384 u16
    const unsigned short* ph = (q < 2) ? &mbuf[t][0][n16][q * 8]
                                       : &hbuf[db][0][n16][(q - 2) * 8];
    U16x8 ah, al;
    ah.v = *(const uint4*)ph;
    al.v = *(const uint4*)(ph + 384);

    f32x4 acc = {bg, bg, bg, bg};
    acc = __builtin_amdgcn_mfma_f32_16x16x32_bf16(ah.b, wf, acc, 0, 0, 0);
    acc = __builtin_amdgcn_mfma_f32_16x16x32_bf16(al.b, wf, acc, 0, 0, 0);

    #pragma unroll
    for (int r = 0; r < 4; r++) pre[wave][q * 4 + r][n16] = acc[r];
    __syncthreads();

    if (tid < 176){
      const float gi = pre[0][nd_o][u_o];
      const float gf = pre[1][nd_o][u_o];
      const float gg = pre[2][nd_o][u_o];
      const float go = pre[3][nd_o][u_o];
      c_o = sigm(gf) * c_o + sigm(gi) * tanh_(gg);
      const float hv = sigm(go) * tanh_(c_o);
      const unsigned short hb = f2b(hv);
      hbuf[nb][0][nd_o][u_o] = hb;
      hbuf[nb][1][nd_o][u_o] = f2b(hv - b2f(hb));
    }
    __syncthreads();
  }

  // ---- epilogue: out[node][uo] = relu(x_self@WsT + bs + hK@WnT) ----
  // A: q<2 -> x_self[node=n16][k], q>=2 -> hK (hbuf[0], written by t=15)
  U16x8 eah, eal;
  if (q < 2){
    const float* row = x + (long)(nb0 + n16) * 11;
    U16x8 H, L;
    #pragma unroll
    for (int j = 0; j < 8; j++){
      const int k = q * 8 + j;
      float v = (k < 11) ? row[k] : 0.f;
      unsigned short hb = f2b(v); H.u[j] = hb; L.u[j] = f2b(v - b2f(hb));
    }
    eah = H; eal = L;
  } else {
    const unsigned short* ph = &hbuf[0][0][n16][(q - 2) * 8];
    eah.v = *(const uint4*)ph;
    eal.v = *(const uint4*)(ph + 384);
  }

  // B: row uo = wave*16+n16 ; q<2 -> Ws[uo][k], q>=2 -> Wn[uo][k-16]
  bf16x8 ewf;
  {
    const int uo = wave * 16 + n16;
    const float* src = (q < 2) ? (Ws + uo * 11) : (Wn + uo * 11);
    const int kb = (q & 1) * 8;
    U16x8 a;
    #pragma unroll
    for (int j = 0; j < 8; j++){
      const int k = kb + j;
      a.u[j] = f2b((k < 11) ? src[k] : 0.f);
    }
    ewf = a.b;
  }

  {
    const int uo = wave * 16 + n16;
    const float bsv = bs[uo];
    f32x4 e = {bsv, bsv, bsv, bsv};
    e = __builtin_amdgcn_mfma_f32_16x16x32_bf16(eah.b, ewf, e, 0, 0, 0);
    e = __builtin_amdgcn_mfma_f32_16x16x32_bf16(eal.b, ewf, e, 0, 0, 0);
    #pragma unroll
    for (int r = 0; r < 4; r++)
      out[(long)(nb0 + q * 4 + r) * 64 + uo] = fmaxf(e[r], 0.f);
  }
}

// ---------------------------------------------------------------------------
// Layers 2/3/4: d=64 LSTM aggregation via MFMA 16x16x32 bf16, hi/lo split on A.
// ---------------------------------------------------------------------------
__global__ __launch_bounds__(256, 3) void sage64_kernel(
    const float* __restrict__ in, const int* __restrict__ nbr,
    const float* __restrict__ Wih, const float* __restrict__ Whh,
    const float* __restrict__ bih, const float* __restrict__ bhh,
    const float* __restrict__ Ws,  const float* __restrict__ bs,
    const float* __restrict__ Wn,
    float* __restrict__ out, int mode)
{
  __shared__ uint4 mfrag[2][2][2][64];
  __shared__ uint4 hfrag[2][2][2][64];
  __shared__ int nbr_s[16 * 17];

  const int tid  = threadIdx.x;
  const int wave = tid >> 6, lane = tid & 63;
  const int n16  = lane & 15, q = lane >> 4;
  const int nb0  = blockIdx.x * 16;

  { const int nd = tid >> 4, t = tid & 15;
    nbr_s[nd * 17 + t] = nbr[(nb0 + nd) * 16 + t]; }

  ((uint4*)hfrag)[tid] = make_uint4(0u, 0u, 0u, 0u);

  {
    const int nd = tid >> 4, k0 = (tid & 15) * 4;
    const int gn = nbr[(nb0 + nd) * 16 + 0];
    float4 v = *(const float4*)(in + (long)gn * 64 + k0);
    unsigned short h0 = f2b(v.x), h1 = f2b(v.y), h2 = f2b(v.z), h3 = f2b(v.w);
    unsigned short l0 = f2b(v.x - b2f(h0)), l1 = f2b(v.y - b2f(h1));
    unsigned short l2 = f2b(v.z - b2f(h2)), l3 = f2b(v.w - b2f(h3));
    const int kc = k0 >> 5, qq = (k0 >> 3) & 3, lp = nd + 16 * qq, half = (k0 & 7) >> 2;
    ((uint2*)&mfrag[0][0][kc][lp])[half] = make_uint2((unsigned)h0 | ((unsigned)h1 << 16),
                                                     (unsigned)h2 | ((unsigned)h3 << 16));
    ((uint2*)&mfrag[0][1][kc][lp])[half] = make_uint2((unsigned)l0 | ((unsigned)l1 << 16),
                                                     (unsigned)l2 | ((unsigned)l3 << 16));
  }

  bf16x8 wih_f[4][2], whh_f[4][2];
  #pragma unroll
  for (int t4 = 0; t4 < 4; t4++){
    const int row = t4 * 64 + wave * 16 + n16;
    #pragma unroll
    for (int kc = 0; kc < 2; kc++){
      wih_f[t4][kc] = load8_bf16(Wih + row * 64 + kc * 32 + q * 8);
      whh_f[t4][kc] = load8_bf16(Whh + row * 64 + kc * 32 + q * 8);
    }
  }
  const int u_ = wave * 16 + n16;
  float b4[4];
  #pragma unroll
  for (int t4 = 0; t4 < 4; t4++) b4[t4] = bih[t4 * 64 + u_] + bhh[t4 * 64 + u_];

  float c4[4] = {0.f, 0.f, 0.f, 0.f};
  const int kch = u_ >> 5, qh = (u_ >> 3) & 3, jh = u_ & 7;

  __syncthreads();

  for (int t = 0; t < 16; t++){
    const int db = t & 1, nbuf = db ^ 1;

    bf16x8 mh[2], ml[2], hh[2], hl[2];
    #pragma unroll
    for (int kc = 0; kc < 2; kc++){
      U16x8 a; a.v = mfrag[db][0][kc][lane]; mh[kc] = a.b;
      U16x8 b_; b_.v = mfrag[db][1][kc][lane]; ml[kc] = b_.b;
      U16x8 cc; cc.v = hfrag[db][0][kc][lane]; hh[kc] = cc.b;
      U16x8 d_; d_.v = hfrag[db][1][kc][lane]; hl[kc] = d_.b;
    }

    float4 gv = make_float4(0.f, 0.f, 0.f, 0.f);
    const int nd = tid >> 4, k0 = (tid & 15) * 4;
    if (t < 15){
      const int gn = nbr_s[nd * 17 + t + 1];
      gv = *(const float4*)(in + (long)gn * 64 + k0);
    }

    f32x4 acc[4];
    #pragma unroll
    for (int t4 = 0; t4 < 4; t4++){ f32x4 av = {b4[t4], b4[t4], b4[t4], b4[t4]}; acc[t4] = av; }
    #pragma unroll
    for (int kc = 0; kc < 2; kc++){
      #pragma unroll
      for (int t4 = 0; t4 < 4; t4++)
        acc[t4] = __builtin_amdgcn_mfma_f32_16x16x32_bf16(mh[kc], wih_f[t4][kc], acc[t4], 0, 0, 0);
      #pragma unroll
      for (int t4 = 0; t4 < 4; t4++)
        acc[t4] = __builtin_amdgcn_mfma_f32_16x16x32_bf16(ml[kc], wih_f[t4][kc], acc[t4], 0, 0, 0);
      #pragma unroll
      for (int t4 = 0; t4 < 4; t4++)
        acc[t4] = __builtin_amdgcn_mfma_f32_16x16x32_bf16(hh[kc], whh_f[t4][kc], acc[t4], 0, 0, 0);
      #pragma unroll
      for (int t4 = 0; t4 < 4; t4++)
        acc[t4] = __builtin_amdgcn_mfma_f32_16x16x32_bf16(hl[kc], whh_f[t4][kc], acc[t4], 0, 0, 0);
    }

    #pragma unroll
    for (int r = 0; r < 4; r++){
      const float iv = sigm(acc[0][r]);
      const float fv = sigm(acc[1][r]);
      const float gg = tanh_(acc[2][r]);
      const float ov = sigm(acc[3][r]);
      c4[r] = fv * c4[r] + iv * gg;
      const float hv = ov * tanh_(c4[r]);
      const unsigned short hb = f2b(hv);
      const unsigned short lb = f2b(hv - b2f(hb));
      const int lp = (q * 4 + r) + 16 * qh;
      ((unsigned short*)&hfrag[nbuf][0][kch][lp])[jh] = hb;
      ((unsigned short*)&hfrag[nbuf][1][kch][lp])[jh] = lb;
    }

    if (t < 15){
      unsigned short h0 = f2b(gv.x), h1 = f2b(gv.y), h2 = f2b(gv.z), h3 = f2b(gv.w);
      unsigned short l0 = f2b(gv.x - b2f(h0)), l1 = f2b(gv.y - b2f(h1));
      unsigned short l2 = f2b(gv.z - b2f(h2)), l3 = f2b(gv.w - b2f(h3));
      const int kc = k0 >> 5, qq = (k0 >> 3) & 3, lp = nd + 16 * qq, half = (k0 & 7) >> 2;
      ((uint2*)&mfrag[nbuf][0][kc][lp])[half] = make_uint2((unsigned)h0 | ((unsigned)h1 << 16),
                                                          (unsigned)h2 | ((unsigned)h3 << 16));
      ((uint2*)&mfrag[nbuf][1][kc][lp])[half] = make_uint2((unsigned)l0 | ((unsigned)l1 << 16),
                                                          (unsigned)l2 | ((unsigned)l3 << 16));
    }
    __syncthreads();
  }

  bf16x8 sh[2], sl[2];
  #pragma unroll
  for (int kc = 0; kc < 2; kc++)
    load8_hilo(in + (long)(nb0 + n16) * 64 + kc * 32 + q * 8, sh[kc], sl[kc]);

  bf16x8 kh[2], kl[2];
  #pragma unroll
  for (int kc = 0; kc < 2; kc++){
    U16x8 a; a.v = hfrag[0][0][kc][lane]; kh[kc] = a.b;
    U16x8 b_; b_.v = hfrag[0][1][kc][lane]; kl[kc] = b_.b;
  }

  if (mode == 0){
    bf16x8 ws_f[2], wn_f[2];
    #pragma unroll
    for (int kc = 0; kc < 2; kc++){
      ws_f[kc] = load8_bf16(Ws + (wave * 16 + n16) * 64 + kc * 32 + q * 8);
      wn_f[kc] = load8_bf16(Wn + (wave * 16 + n16) * 64 + kc * 32 + q * 8);
    }
    f32x4 e = {0.f, 0.f, 0.f, 0.f};
    #pragma unroll
    for (int kc = 0; kc < 2; kc++){
      e = __builtin_amdgcn_mfma_f32_16x16x32_bf16(sh[kc], ws_f[kc], e, 0, 0, 0);
      e = __builtin_amdgcn_mfma_f32_16x16x32_bf16(sl[kc], ws_f[kc], e, 0, 0, 0);
      e = __builtin_amdgcn_mfma_f32_16x16x32_bf16(kh[kc], wn_f[kc], e, 0, 0, 0);
      e = __builtin_amdgcn_mfma_f32_16x16x32_bf16(kl[kc], wn_f[kc], e, 0, 0, 0);
    }
    const int col = wave * 16 + n16;
    const float bsv = bs[col];
    #pragma unroll
    for (int r = 0; r < 4; r++)
      out[(long)(nb0 + q * 4 + r) * 64 + col] = fmaxf(e[r] + bsv, 0.f);
  } else {
    if (wave == 0){
      bf16x8 ws_f[2], wn_f[2];
      #pragma unroll
      for (int kc = 0; kc < 2; kc++){
        U16x8 a, b_;
        a.v = make_uint4(0u,0u,0u,0u); b_.v = make_uint4(0u,0u,0u,0u);
        if (n16 == 0){
          a.b  = load8_bf16(Ws + kc * 32 + q * 8);
          b_.b = load8_bf16(Wn + kc * 32 + q * 8);
        }
        ws_f[kc] = a.b; wn_f[kc] = b_.b;
      }
      f32x4 e = {0.f, 0.f, 0.f, 0.f};
      #pragma unroll
      for (int kc = 0; kc < 2; kc++){
        e = __builtin_amdgcn_mfma_f32_16x16x32_bf16(sh[kc], ws_f[kc], e, 0, 0, 0);
        e = __builtin_amdgcn_mfma_f32_16x16x32_bf16(sl[kc], ws_f[kc], e, 0, 0, 0);
        e = __builtin_amdgcn_mfma_f32_16x16x32_bf16(kh[kc], wn_f[kc], e, 0, 0, 0);
        e = __builtin_amdgcn_mfma_f32_16x16x32_bf16(kl[kc], wn_f[kc], e, 0, 0, 0);
      }
      if (n16 == 0){
        const float bsv = bs[0];
        #pragma unroll
        for (int r = 0; r < 4; r++)
          out[nb0 + q * 4 + r] = e[r] + bsv;
      }
    }
  }
}

// ---------------------------------------------------------------------------
// GRU cell (one shot): h = (1-z)*n + z*prev. MFMA, no LDS.
// ---------------------------------------------------------------------------
__global__ __launch_bounds__(256) void gru_kernel(
    const float* __restrict__ h3, const float* __restrict__ prev,
    const float* __restrict__ gWih, const float* __restrict__ gWhh,
    const float* __restrict__ gbih, const float* __restrict__ gbhh,
    float* __restrict__ out)
{
  const int tid = threadIdx.x, wave = tid >> 6, lane = tid & 63;
  const int n16 = lane & 15, q = lane >> 4;
  const int nb0 = blockIdx.x * 16;
  const int u_ = wave * 16 + n16;

  bf16x8 ah[2], al[2], ap[2];
  #pragma unroll
  for (int kc = 0; kc < 2; kc++){
    load8_hilo(h3 + (long)(nb0 + n16) * 64 + kc * 32 + q * 8, ah[kc], al[kc]);
    ap[kc] = load8_bf16(prev + (long)(nb0 + n16) * 64 + kc * 32 + q * 8);
  }

  bf16x8 wi_f[3][2], wh_f[3][2];
  #pragma unroll
  for (int g = 0; g < 3; g++){
    const int row = g * 64 + wave * 16 + n16;
    #pragma unroll
    for (int kc = 0; kc < 2; kc++){
      wi_f[g][kc] = load8_bf16(gWih + row * 64 + kc * 32 + q * 8);
      wh_f[g][kc] = load8_bf16(gWhh + row * 64 + kc * 32 + q * 8);
    }
  }

  f32x4 gi[3], gh[3];
  #pragma unroll
  for (int g = 0; g < 3; g++){
    const float bi = gbih[g * 64 + u_], bh = gbhh[g * 64 + u_];
    f32x4 vi = {bi, bi, bi, bi}; gi[g] = vi;
    f32x4 vh = {bh, bh, bh, bh}; gh[g] = vh;
  }
  #pragma unroll
  for (int kc = 0; kc < 2; kc++){
    #pragma unroll
    for (int g = 0; g < 3; g++)
      gi[g] = __builtin_amdgcn_mfma_f32_16x16x32_bf16(ah[kc], wi_f[g][kc], gi[g], 0, 0, 0);
    #pragma unroll
    for (int g = 0; g < 3; g++)
      gi[g] = __builtin_amdgcn_mfma_f32_16x16x32_bf16(al[kc], wi_f[g][kc], gi[g], 0, 0, 0);
    #pragma unroll
    for (int g = 0; g < 3; g++)
      gh[g] = __builtin_amdgcn_mfma_f32_16x16x32_bf16(ap[kc], wh_f[g][kc], gh[g], 0, 0, 0);
  }

  #pragma unroll
  for (int r = 0; r < 4; r++){
    const long node = nb0 + q * 4 + r;
    const float rv = sigm(gi[0][r] + gh[0][r]);
    const float zv = sigm(gi[1][r] + gh[1][r]);
    const float nv = tanh_(gi[2][r] + rv * gh[2][r]);
    const float hp = prev[node * 64 + u_];
    out[node * 64 + u_] = (1.f - zv) * nv + zv * hp;
  }
}

// ---------------------------------------------------------------------------
extern "C" void kernel_launch(void* const* d_in, const int* in_sizes, int n_in,
                              void* d_out, int out_size, void* d_ws, size_t ws_size,
                              hipStream_t stream)
{
  (void)in_sizes; (void)n_in; (void)out_size; (void)ws_size;
  const float* x    = (const float*)d_in[0];
  const int*   nbr  = (const int*)d_in[1];
  const float* prev = (const float*)d_in[2];
  auto W = [&](int i){ return (const float*)d_in[i]; };

  float* bufA = (float*)d_ws;                      // 50000*64 fp32 = 12.8 MB
  float* bufB = bufA + (size_t)N_NODES * 64;       // second 12.8 MB

  // layer 1 (d=11, MFMA): x -> bufA (=h1)
  l1_kernel<<<N_NODES / 16, 256, 0, stream>>>(
      x, nbr, W(3), W(4), W(5), W(6), W(7), W(8), W(9), bufA);
  // layer 2: bufA -> bufB (=h2)
  sage64_kernel<<<N_NODES / 16, 256, 0, stream>>>(
      bufA, nbr, W(10), W(11), W(12), W(13), W(14), W(15), W(16), bufB, 0);
  // layer 3: bufB -> bufA (=h3)
  sage64_kernel<<<N_NODES / 16, 256, 0, stream>>>(
      bufB, nbr, W(17), W(18), W(19), W(20), W(21), W(22), W(23), bufA, 0);
  // GRU: (h3=bufA, prev) -> bufB (=h)
  gru_kernel<<<N_NODES / 16, 256, 0, stream>>>(
      bufA, prev, W(31), W(32), W(33), W(34), bufB);
  // layer 4 (o=1): bufB -> d_out (fp32 logits)
  sage64_kernel<<<N_NODES / 16, 256, 0, stream>>>(
      bufB, nbr, W(24), W(25), W(26), W(27), W(28), W(29), W(30),
      (float*)d_out, 1);
}

// Round 4
// 598.456 us; speedup vs baseline: 2.9505x; 1.3919x over previous
//
#include <hip/hip_runtime.h>

#define N_NODES 50000

typedef __bf16 bf16x8 __attribute__((ext_vector_type(8)));
typedef float f32x4 __attribute__((ext_vector_type(4)));

union U16x8 { uint4 v; unsigned short u[8]; bf16x8 b; };

__device__ __forceinline__ float b2f(unsigned short h){
  unsigned int u = ((unsigned int)h) << 16;
  return __builtin_bit_cast(float, u);
}
__device__ __forceinline__ unsigned short f2b(float x){
  unsigned int u = __builtin_bit_cast(unsigned int, x);
  u = u + 0x7FFFu + ((u >> 16) & 1u);
  return (unsigned short)(u >> 16);
}
// raw-hardware sigmoid/tanh: v_exp_f32 + v_rcp_f32, no division refinement.
// Saturation is exact through inf: exp2(+inf)->inf, rcp(inf)->0.
__device__ __forceinline__ float sigm(float x){
  const float e = __builtin_amdgcn_exp2f(x * -1.4426950408889634f);
  return __builtin_amdgcn_rcpf(1.0f + e);
}
__device__ __forceinline__ float tanh_(float x){
  const float e = __builtin_amdgcn_exp2f(x * 2.8853900817779268f);
  return fmaf(-2.0f, __builtin_amdgcn_rcpf(1.0f + e), 1.0f);
}

// 8 consecutive f32 -> bf16x8 (RNE), hi only
__device__ __forceinline__ bf16x8 load8_bf16(const float* p){
  float4 a = *(const float4*)p; float4 c = *(const float4*)(p + 4);
  U16x8 r;
  r.u[0]=f2b(a.x); r.u[1]=f2b(a.y); r.u[2]=f2b(a.z); r.u[3]=f2b(a.w);
  r.u[4]=f2b(c.x); r.u[5]=f2b(c.y); r.u[6]=f2b(c.z); r.u[7]=f2b(c.w);
  return r.b;
}

// ---------------------------------------------------------------------------
// Activation table format (all inter-layer tensors), u16[node][128]:
//   [0..63]  = bf16 hi of the fp32 row
//   [64..127]= bf16 lo (residual), x ~= hi + lo  (~2^-18 accurate)
// 16B slot s of a row: s=0..7 hi features 8s..8s+7 ; s=8..15 lo features.
// B-frag read (lane n16=node, q): hi slot kc*4+q, lo slot 8+kc*4+q.
// ---------------------------------------------------------------------------

// ---------------------------------------------------------------------------
// Layer 1 (d=11) via MFMA: unchanged internals; epilogue writes hilo table.
// ---------------------------------------------------------------------------
__global__ __launch_bounds__(256) void l1_kernel(
    const float* __restrict__ x, const int* __restrict__ nbr,
    const float* __restrict__ Wih, const float* __restrict__ Whh,
    const float* __restrict__ bih, const float* __restrict__ bhh,
    const float* __restrict__ Ws,  const float* __restrict__ bs,
    const float* __restrict__ Wn,  unsigned short* __restrict__ out_hl)
{
  __shared__ unsigned short mbuf[16][2][16][24];
  __shared__ unsigned short hbuf[2][2][16][24];
  __shared__ float pre[4][16][17];

  const int tid  = threadIdx.x;
  const int wave = tid >> 6, lane = tid & 63;
  const int n16  = lane & 15, q = lane >> 4;
  const int nb0  = blockIdx.x * 16;

  { unsigned int* p = (unsigned int*)hbuf;
    for (int i = tid; i < 768; i += 256) p[i] = 0u; }

  {
    const int nd = tid >> 4, t = tid & 15;
    const int gn = nbr[(nb0 + nd) * 16 + t];
    const float* row = x + (long)gn * 11;
    float v[16];
    #pragma unroll
    for (int j = 0; j < 11; j++) v[j] = row[j];
    #pragma unroll
    for (int j = 11; j < 16; j++) v[j] = 0.f;
    #pragma unroll
    for (int j = 0; j < 16; j++){
      unsigned short hb = f2b(v[j]);
      mbuf[t][0][nd][j] = hb;
      mbuf[t][1][nd][j] = f2b(v[j] - b2f(hb));
    }
  }

  bf16x8 wf;
  {
    const int u = n16;
    const float* src = (q < 2) ? (Wih + (wave * 11 + u) * 11)
                               : (Whh + (wave * 11 + u) * 11);
    const int kb = (q & 1) * 8;
    U16x8 a;
    #pragma unroll
    for (int j = 0; j < 8; j++){
      const int k = kb + j;
      float v = (u < 11 && k < 11) ? src[k] : 0.f;
      a.u[j] = f2b(v);
    }
    wf = a.b;
  }
  const float bg = (n16 < 11) ? (bih[wave * 11 + n16] + bhh[wave * 11 + n16]) : 0.f;

  const int nd_o = tid & 15, u_o = tid >> 4;
  float c_o = 0.f;

  __syncthreads();

  for (int t = 0; t < 16; t++){
    const int db = t & 1, nb = db ^ 1;

    const unsigned short* ph = (q < 2) ? &mbuf[t][0][n16][q * 8]
                                       : &hbuf[db][0][n16][(q - 2) * 8];
    U16x8 ah, al;
    ah.v = *(const uint4*)ph;
    al.v = *(const uint4*)(ph + 384);

    f32x4 acc = {bg, bg, bg, bg};
    acc = __builtin_amdgcn_mfma_f32_16x16x32_bf16(ah.b, wf, acc, 0, 0, 0);
    acc = __builtin_amdgcn_mfma_f32_16x16x32_bf16(al.b, wf, acc, 0, 0, 0);

    #pragma unroll
    for (int r = 0; r < 4; r++) pre[wave][q * 4 + r][n16] = acc[r];
    __syncthreads();

    if (tid < 176){
      const float gi = pre[0][nd_o][u_o];
      const float gf = pre[1][nd_o][u_o];
      const float gg = pre[2][nd_o][u_o];
      const float go = pre[3][nd_o][u_o];
      c_o = sigm(gf) * c_o + sigm(gi) * tanh_(gg);
      const float hv = sigm(go) * tanh_(c_o);
      const unsigned short hb = f2b(hv);
      hbuf[nb][0][nd_o][u_o] = hb;
      hbuf[nb][1][nd_o][u_o] = f2b(hv - b2f(hb));
    }
    __syncthreads();
  }

  U16x8 eah, eal;
  if (q < 2){
    const float* row = x + (long)(nb0 + n16) * 11;
    U16x8 H, L;
    #pragma unroll
    for (int j = 0; j < 8; j++){
      const int k = q * 8 + j;
      float v = (k < 11) ? row[k] : 0.f;
      unsigned short hb = f2b(v); H.u[j] = hb; L.u[j] = f2b(v - b2f(hb));
    }
    eah = H; eal = L;
  } else {
    const unsigned short* ph = &hbuf[0][0][n16][(q - 2) * 8];
    eah.v = *(const uint4*)ph;
    eal.v = *(const uint4*)(ph + 384);
  }

  bf16x8 ewf;
  {
    const int uo = wave * 16 + n16;
    const float* src = (q < 2) ? (Ws + uo * 11) : (Wn + uo * 11);
    const int kb = (q & 1) * 8;
    U16x8 a;
    #pragma unroll
    for (int j = 0; j < 8; j++){
      const int k = kb + j;
      a.u[j] = f2b((k < 11) ? src[k] : 0.f);
    }
    ewf = a.b;
  }

  {
    const int uo = wave * 16 + n16;
    const float bsv = bs[uo];
    f32x4 e = {bsv, bsv, bsv, bsv};
    e = __builtin_amdgcn_mfma_f32_16x16x32_bf16(eah.b, ewf, e, 0, 0, 0);
    e = __builtin_amdgcn_mfma_f32_16x16x32_bf16(eal.b, ewf, e, 0, 0, 0);
    #pragma unroll
    for (int r = 0; r < 4; r++){
      const float vv = fmaxf(e[r], 0.f);
      const unsigned short hb = f2b(vv);
      const size_t base = (size_t)(nb0 + q * 4 + r) * 128;
      out_hl[base + uo]      = hb;
      out_hl[base + 64 + uo] = f2b(vv - b2f(hb));
    }
  }
}

// ---------------------------------------------------------------------------
// Layers 2/3/4: transposed MFMA orientation. A = weights (rows=units),
// B = [m;h] (cols=nodes). Wave wv owns unit-tile wv (16 units, all 4 gates).
// Lane (n16=node, q): gate outputs for units wv*16+q*4..+3 of node n16 ->
// h-writeback is 2x ds_write_b64, contiguous. B-frags in 17x16B padded rows
// (conflict-free b128 reads/writes). Input/output are hilo tables.
// mode 0: out_hl = relu(hself@WsT + bs + hK@WnT) as hilo table
// mode 1: out_f32[n] = hself@WsT + bs + hK@WnT (o=1)
// ---------------------------------------------------------------------------
__global__ __launch_bounds__(256, 3) void sage64_kernel(
    const unsigned short* __restrict__ in_hl, const int* __restrict__ nbr,
    const float* __restrict__ Wih, const float* __restrict__ Whh,
    const float* __restrict__ bih, const float* __restrict__ bhh,
    const float* __restrict__ Ws,  const float* __restrict__ bs,
    const float* __restrict__ Wn,
    unsigned short* __restrict__ out_hl, float* __restrict__ out_f32, int mode)
{
  __shared__ uint4 mbuf[2][16][17];   // [dbuf][node][slot] 16 used + 1 pad
  __shared__ uint4 hbuf[2][16][17];
  __shared__ int nbr_s[16 * 17];

  const int tid = threadIdx.x;
  const int wv = tid >> 6, lane = tid & 63;
  const int n16 = lane & 15, q = lane >> 4;
  const int nb0 = blockIdx.x * 16;

  { const int nd = tid >> 4, t = tid & 15;
    nbr_s[nd * 17 + t] = nbr[(nb0 + nd) * 16 + t]; }

  // zero hbuf[0] (initial h = 0): 16*17 uint4 = 1088 uints
  { unsigned int* p = (unsigned int*)&hbuf[0][0][0];
    for (int i = tid; i < 1088; i += 256) p[i] = 0u; }

  // gather m_0: thread (nd, s) -> 16B slot s of neighbor row
  { const int nd = tid >> 4, s = tid & 15;
    const int gn = nbr[(nb0 + nd) * 16 + 0];
    mbuf[0][nd][s] = *(const uint4*)(in_hl + (size_t)gn * 128 + s * 8); }

  // resident weight A-frags: gate g, kc; lane row = unit wv*16+n16
  bf16x8 wih_f[4][2], whh_f[4][2];
  #pragma unroll
  for (int g = 0; g < 4; g++){
    const int row = g * 64 + wv * 16 + n16;
    #pragma unroll
    for (int kc = 0; kc < 2; kc++){
      wih_f[g][kc] = load8_bf16(Wih + row * 64 + kc * 32 + q * 8);
      whh_f[g][kc] = load8_bf16(Whh + row * 64 + kc * 32 + q * 8);
    }
  }
  // biases for this lane's 4 units (rows q*4+r of tile wv), all 4 gates
  f32x4 bg[4];
  #pragma unroll
  for (int g = 0; g < 4; g++){
    float4 bi = *(const float4*)(bih + g * 64 + wv * 16 + q * 4);
    float4 bh = *(const float4*)(bhh + g * 64 + wv * 16 + q * 4);
    f32x4 s = {bi.x + bh.x, bi.y + bh.y, bi.z + bh.z, bi.w + bh.w};
    bg[g] = s;
  }

  float c4[4] = {0.f, 0.f, 0.f, 0.f};
  __syncthreads();

  for (int t = 0; t < 16; t++){
    const int db = t & 1, nbf = db ^ 1;

    // B-frags (shared across waves): m and h, hi/lo
    bf16x8 mh[2], ml[2], hh[2], hl[2];
    #pragma unroll
    for (int kc = 0; kc < 2; kc++){
      U16x8 a; a.v = mbuf[db][n16][kc * 4 + q];     mh[kc] = a.b;
      U16x8 b_; b_.v = mbuf[db][n16][8 + kc * 4 + q]; ml[kc] = b_.b;
      U16x8 c_; c_.v = hbuf[db][n16][kc * 4 + q];     hh[kc] = c_.b;
      U16x8 d_; d_.v = hbuf[db][n16][8 + kc * 4 + q]; hl[kc] = d_.b;
    }

    // issue gather for m_{t+1} (consumed after MFMAs)
    uint4 gv = make_uint4(0u, 0u, 0u, 0u);
    const int nd = tid >> 4, s = tid & 15;
    if (t < 15){
      const int gn = nbr_s[nd * 17 + t + 1];
      gv = *(const uint4*)(in_hl + (size_t)gn * 128 + s * 8);
    }

    f32x4 acc[4];
    #pragma unroll
    for (int g = 0; g < 4; g++) acc[g] = bg[g];
    #pragma unroll
    for (int kc = 0; kc < 2; kc++){
      #pragma unroll
      for (int g = 0; g < 4; g++)
        acc[g] = __builtin_amdgcn_mfma_f32_16x16x32_bf16(wih_f[g][kc], mh[kc], acc[g], 0, 0, 0);
      #pragma unroll
      for (int g = 0; g < 4; g++)
        acc[g] = __builtin_amdgcn_mfma_f32_16x16x32_bf16(wih_f[g][kc], ml[kc], acc[g], 0, 0, 0);
      #pragma unroll
      for (int g = 0; g < 4; g++)
        acc[g] = __builtin_amdgcn_mfma_f32_16x16x32_bf16(whh_f[g][kc], hh[kc], acc[g], 0, 0, 0);
      #pragma unroll
      for (int g = 0; g < 4; g++)
        acc[g] = __builtin_amdgcn_mfma_f32_16x16x32_bf16(whh_f[g][kc], hl[kc], acc[g], 0, 0, 0);
    }

    // gates: lane (n16=node, q) holds i/f/g/o for units wv*16+q*4+r
    unsigned short hB[4], lB[4];
    #pragma unroll
    for (int r = 0; r < 4; r++){
      const float iv = sigm(acc[0][r]);
      const float fv = sigm(acc[1][r]);
      const float gg = tanh_(acc[2][r]);
      const float ov = sigm(acc[3][r]);
      c4[r] = fv * c4[r] + iv * gg;
      const float hv = ov * tanh_(c4[r]);
      hB[r] = f2b(hv);
      lB[r] = f2b(hv - b2f(hB[r]));
    }
    {
      uint2* hrow = (uint2*)&hbuf[nbf][n16][0];
      hrow[wv * 4 + q]      = make_uint2((unsigned)hB[0] | ((unsigned)hB[1] << 16),
                                         (unsigned)hB[2] | ((unsigned)hB[3] << 16));
      hrow[16 + wv * 4 + q] = make_uint2((unsigned)lB[0] | ((unsigned)lB[1] << 16),
                                         (unsigned)lB[2] | ((unsigned)lB[3] << 16));
    }
    if (t < 15) mbuf[nbf][nd][s] = gv;
    __syncthreads();
  }

  // ---- epilogue: B = [hself ; hK] hi/lo ----
  bf16x8 sH[2], sL[2], kH[2], kL[2];
  #pragma unroll
  for (int kc = 0; kc < 2; kc++){
    U16x8 a; a.v = *(const uint4*)(in_hl + (size_t)(nb0 + n16) * 128 + kc * 32 + q * 8);
    sH[kc] = a.b;
    U16x8 b_; b_.v = *(const uint4*)(in_hl + (size_t)(nb0 + n16) * 128 + 64 + kc * 32 + q * 8);
    sL[kc] = b_.b;
    U16x8 c_; c_.v = hbuf[0][n16][kc * 4 + q];     kH[kc] = c_.b;
    U16x8 d_; d_.v = hbuf[0][n16][8 + kc * 4 + q]; kL[kc] = d_.b;
  }

  if (mode == 0){
    bf16x8 ws_f[2], wn_f[2];
    #pragma unroll
    for (int kc = 0; kc < 2; kc++){
      ws_f[kc] = load8_bf16(Ws + (wv * 16 + n16) * 64 + kc * 32 + q * 8);
      wn_f[kc] = load8_bf16(Wn + (wv * 16 + n16) * 64 + kc * 32 + q * 8);
    }
    float4 bsv = *(const float4*)(bs + wv * 16 + q * 4);
    f32x4 e = {bsv.x, bsv.y, bsv.z, bsv.w};
    #pragma unroll
    for (int kc = 0; kc < 2; kc++){
      e = __builtin_amdgcn_mfma_f32_16x16x32_bf16(ws_f[kc], sH[kc], e, 0, 0, 0);
      e = __builtin_amdgcn_mfma_f32_16x16x32_bf16(ws_f[kc], sL[kc], e, 0, 0, 0);
      e = __builtin_amdgcn_mfma_f32_16x16x32_bf16(wn_f[kc], kH[kc], e, 0, 0, 0);
      e = __builtin_amdgcn_mfma_f32_16x16x32_bf16(wn_f[kc], kL[kc], e, 0, 0, 0);
    }
    unsigned short hB[4], lB[4];
    #pragma unroll
    for (int r = 0; r < 4; r++){
      const float vv = fmaxf(e[r], 0.f);
      hB[r] = f2b(vv);
      lB[r] = f2b(vv - b2f(hB[r]));
    }
    uint2* orow = (uint2*)(out_hl + (size_t)(nb0 + n16) * 128);
    orow[wv * 4 + q]      = make_uint2((unsigned)hB[0] | ((unsigned)hB[1] << 16),
                                       (unsigned)hB[2] | ((unsigned)hB[3] << 16));
    orow[16 + wv * 4 + q] = make_uint2((unsigned)lB[0] | ((unsigned)lB[1] << 16),
                                       (unsigned)lB[2] | ((unsigned)lB[3] << 16));
  } else {
    if (wv == 0){
      bf16x8 ws_f[2], wn_f[2];
      #pragma unroll
      for (int kc = 0; kc < 2; kc++){
        U16x8 a, b_;
        a.v = make_uint4(0u,0u,0u,0u); b_.v = make_uint4(0u,0u,0u,0u);
        if (n16 == 0){
          a.b  = load8_bf16(Ws + kc * 32 + q * 8);
          b_.b = load8_bf16(Wn + kc * 32 + q * 8);
        }
        ws_f[kc] = a.b; wn_f[kc] = b_.b;
      }
      f32x4 e = {0.f, 0.f, 0.f, 0.f};
      #pragma unroll
      for (int kc = 0; kc < 2; kc++){
        e = __builtin_amdgcn_mfma_f32_16x16x32_bf16(ws_f[kc], sH[kc], e, 0, 0, 0);
        e = __builtin_amdgcn_mfma_f32_16x16x32_bf16(ws_f[kc], sL[kc], e, 0, 0, 0);
        e = __builtin_amdgcn_mfma_f32_16x16x32_bf16(wn_f[kc], kH[kc], e, 0, 0, 0);
        e = __builtin_amdgcn_mfma_f32_16x16x32_bf16(wn_f[kc], kL[kc], e, 0, 0, 0);
      }
      if (q == 0) out_f32[nb0 + n16] = e[0] + bs[0];
    }
  }
}

// ---------------------------------------------------------------------------
// GRU cell: inputs h3 (hilo table) + prev (fp32); output hilo table.
// Old (untransposed) orientation: A rows = nodes, B = weight rows.
// ---------------------------------------------------------------------------
__global__ __launch_bounds__(256) void gru_kernel(
    const unsigned short* __restrict__ h3_hl, const float* __restrict__ prev,
    const float* __restrict__ gWih, const float* __restrict__ gWhh,
    const float* __restrict__ gbih, const float* __restrict__ gbhh,
    unsigned short* __restrict__ out_hl)
{
  const int tid = threadIdx.x, wave = tid >> 6, lane = tid & 63;
  const int n16 = lane & 15, q = lane >> 4;
  const int nb0 = blockIdx.x * 16;
  const int u_ = wave * 16 + n16;

  bf16x8 ah[2], al[2], ap[2];
  #pragma unroll
  for (int kc = 0; kc < 2; kc++){
    U16x8 a; a.v = *(const uint4*)(h3_hl + (size_t)(nb0 + n16) * 128 + kc * 32 + q * 8);
    ah[kc] = a.b;
    U16x8 b_; b_.v = *(const uint4*)(h3_hl + (size_t)(nb0 + n16) * 128 + 64 + kc * 32 + q * 8);
    al[kc] = b_.b;
    ap[kc] = load8_bf16(prev + (size_t)(nb0 + n16) * 64 + kc * 32 + q * 8);
  }

  bf16x8 wi_f[3][2], wh_f[3][2];
  #pragma unroll
  for (int g = 0; g < 3; g++){
    const int row = g * 64 + wave * 16 + n16;
    #pragma unroll
    for (int kc = 0; kc < 2; kc++){
      wi_f[g][kc] = load8_bf16(gWih + row * 64 + kc * 32 + q * 8);
      wh_f[g][kc] = load8_bf16(gWhh + row * 64 + kc * 32 + q * 8);
    }
  }

  f32x4 gi[3], gh[3];
  #pragma unroll
  for (int g = 0; g < 3; g++){
    const float bi = gbih[g * 64 + u_], bh = gbhh[g * 64 + u_];
    f32x4 vi = {bi, bi, bi, bi}; gi[g] = vi;
    f32x4 vh = {bh, bh, bh, bh}; gh[g] = vh;
  }
  #pragma unroll
  for (int kc = 0; kc < 2; kc++){
    #pragma unroll
    for (int g = 0; g < 3; g++)
      gi[g] = __builtin_amdgcn_mfma_f32_16x16x32_bf16(ah[kc], wi_f[g][kc], gi[g], 0, 0, 0);
    #pragma unroll
    for (int g = 0; g < 3; g++)
      gi[g] = __builtin_amdgcn_mfma_f32_16x16x32_bf16(al[kc], wi_f[g][kc], gi[g], 0, 0, 0);
    #pragma unroll
    for (int g = 0; g < 3; g++)
      gh[g] = __builtin_amdgcn_mfma_f32_16x16x32_bf16(ap[kc], wh_f[g][kc], gh[g], 0, 0, 0);
  }

  #pragma unroll
  for (int r = 0; r < 4; r++){
    const long node = nb0 + q * 4 + r;
    const float rv = sigm(gi[0][r] + gh[0][r]);
    const float zv = sigm(gi[1][r] + gh[1][r]);
    const float nv = tanh_(gi[2][r] + rv * gh[2][r]);
    const float hp = prev[node * 64 + u_];
    const float v = (1.f - zv) * nv + zv * hp;
    const unsigned short hb = f2b(v);
    out_hl[(size_t)node * 128 + u_]      = hb;
    out_hl[(size_t)node * 128 + 64 + u_] = f2b(v - b2f(hb));
  }
}

// ---------------------------------------------------------------------------
extern "C" void kernel_launch(void* const* d_in, const int* in_sizes, int n_in,
                              void* d_out, int out_size, void* d_ws, size_t ws_size,
                              hipStream_t stream)
{
  (void)in_sizes; (void)n_in; (void)out_size; (void)ws_size;
  const float* x    = (const float*)d_in[0];
  const int*   nbr  = (const int*)d_in[1];
  const float* prev = (const float*)d_in[2];
  auto W = [&](int i){ return (const float*)d_in[i]; };

  unsigned short* tabA = (unsigned short*)d_ws;            // [N][128] hilo, 12.8 MB
  unsigned short* tabB = tabA + (size_t)N_NODES * 128;     // second table

  // layer 1 (d=11): x -> tabA (=h1 hilo)
  l1_kernel<<<N_NODES / 16, 256, 0, stream>>>(
      x, nbr, W(3), W(4), W(5), W(6), W(7), W(8), W(9), tabA);
  // layer 2: tabA -> tabB
  sage64_kernel<<<N_NODES / 16, 256, 0, stream>>>(
      tabA, nbr, W(10), W(11), W(12), W(13), W(14), W(15), W(16), tabB, nullptr, 0);
  // layer 3: tabB -> tabA
  sage64_kernel<<<N_NODES / 16, 256, 0, stream>>>(
      tabB, nbr, W(17), W(18), W(19), W(20), W(21), W(22), W(23), tabA, nullptr, 0);
  // GRU: (h3=tabA, prev) -> tabB
  gru_kernel<<<N_NODES / 16, 256, 0, stream>>>(
      tabA, prev, W(31), W(32), W(33), W(34), tabB);
  // layer 4 (o=1): tabB -> d_out (fp32 logits)
  sage64_kernel<<<N_NODES / 16, 256, 0, stream>>>(
      tabB, nbr, W(24), W(25), W(26), W(27), W(28), W(29), W(30),
      nullptr, (float*)d_out, 1);
}

// Round 5
// 591.715 us; speedup vs baseline: 2.9841x; 1.0114x over previous
//
#include <hip/hip_runtime.h>

#define N_NODES 50000

typedef __bf16 bf16x8 __attribute__((ext_vector_type(8)));
typedef float f32x4 __attribute__((ext_vector_type(4)));

union U16x8 { uint4 v; unsigned short u[8]; bf16x8 b; };

__device__ __forceinline__ float b2f(unsigned short h){
  unsigned int u = ((unsigned int)h) << 16;
  return __builtin_bit_cast(float, u);
}
__device__ __forceinline__ unsigned short f2b(float x){
  unsigned int u = __builtin_bit_cast(unsigned int, x);
  u = u + 0x7FFFu + ((u >> 16) & 1u);
  return (unsigned short)(u >> 16);
}
// raw-hardware sigmoid/tanh: v_exp_f32 + v_rcp_f32, no division refinement.
__device__ __forceinline__ float sigm(float x){
  const float e = __builtin_amdgcn_exp2f(x * -1.4426950408889634f);
  return __builtin_amdgcn_rcpf(1.0f + e);
}
__device__ __forceinline__ float tanh_(float x){
  const float e = __builtin_amdgcn_exp2f(x * 2.8853900817779268f);
  return fmaf(-2.0f, __builtin_amdgcn_rcpf(1.0f + e), 1.0f);
}

// 8 consecutive f32 -> bf16x8 (RNE), hi only
__device__ __forceinline__ bf16x8 load8_bf16(const float* p){
  float4 a = *(const float4*)p; float4 c = *(const float4*)(p + 4);
  U16x8 r;
  r.u[0]=f2b(a.x); r.u[1]=f2b(a.y); r.u[2]=f2b(a.z); r.u[3]=f2b(a.w);
  r.u[4]=f2b(c.x); r.u[5]=f2b(c.y); r.u[6]=f2b(c.z); r.u[7]=f2b(c.w);
  return r.b;
}

// ---------------------------------------------------------------------------
// Activation tables (all inter-layer tensors): u16[node][64], bf16 hi of fp32.
// ---------------------------------------------------------------------------

// ---------------------------------------------------------------------------
// Layer 1 (d=11) via MFMA; internals keep hi/lo (cheap at d=11).
// Epilogue writes the u16 hi table.
// ---------------------------------------------------------------------------
__global__ __launch_bounds__(256) void l1_kernel(
    const float* __restrict__ x, const int* __restrict__ nbr,
    const float* __restrict__ Wih, const float* __restrict__ Whh,
    const float* __restrict__ bih, const float* __restrict__ bhh,
    const float* __restrict__ Ws,  const float* __restrict__ bs,
    const float* __restrict__ Wn,  unsigned short* __restrict__ out_hl)
{
  __shared__ unsigned short mbuf[16][2][16][24];
  __shared__ unsigned short hbuf[2][2][16][24];
  __shared__ float pre[4][16][17];

  const int tid  = threadIdx.x;
  const int wave = tid >> 6, lane = tid & 63;
  const int n16  = lane & 15, q = lane >> 4;
  const int nb0  = blockIdx.x * 16;

  { unsigned int* p = (unsigned int*)hbuf;
    for (int i = tid; i < 768; i += 256) p[i] = 0u; }

  {
    const int nd = tid >> 4, t = tid & 15;
    const int gn = nbr[(nb0 + nd) * 16 + t];
    const float* row = x + (long)gn * 11;
    float v[16];
    #pragma unroll
    for (int j = 0; j < 11; j++) v[j] = row[j];
    #pragma unroll
    for (int j = 11; j < 16; j++) v[j] = 0.f;
    #pragma unroll
    for (int j = 0; j < 16; j++){
      unsigned short hb = f2b(v[j]);
      mbuf[t][0][nd][j] = hb;
      mbuf[t][1][nd][j] = f2b(v[j] - b2f(hb));
    }
  }

  bf16x8 wf;
  {
    const int u = n16;
    const float* src = (q < 2) ? (Wih + (wave * 11 + u) * 11)
                               : (Whh + (wave * 11 + u) * 11);
    const int kb = (q & 1) * 8;
    U16x8 a;
    #pragma unroll
    for (int j = 0; j < 8; j++){
      const int k = kb + j;
      float v = (u < 11 && k < 11) ? src[k] : 0.f;
      a.u[j] = f2b(v);
    }
    wf = a.b;
  }
  const float bg = (n16 < 11) ? (bih[wave * 11 + n16] + bhh[wave * 11 + n16]) : 0.f;

  const int nd_o = tid & 15, u_o = tid >> 4;
  float c_o = 0.f;

  __syncthreads();

  for (int t = 0; t < 16; t++){
    const int db = t & 1, nb = db ^ 1;

    const unsigned short* ph = (q < 2) ? &mbuf[t][0][n16][q * 8]
                                       : &hbuf[db][0][n16][(q - 2) * 8];
    U16x8 ah, al;
    ah.v = *(const uint4*)ph;
    al.v = *(const uint4*)(ph + 384);

    f32x4 acc = {bg, bg, bg, bg};
    acc = __builtin_amdgcn_mfma_f32_16x16x32_bf16(ah.b, wf, acc, 0, 0, 0);
    acc = __builtin_amdgcn_mfma_f32_16x16x32_bf16(al.b, wf, acc, 0, 0, 0);

    #pragma unroll
    for (int r = 0; r < 4; r++) pre[wave][q * 4 + r][n16] = acc[r];
    __syncthreads();

    if (tid < 176){
      const float gi = pre[0][nd_o][u_o];
      const float gf = pre[1][nd_o][u_o];
      const float gg = pre[2][nd_o][u_o];
      const float go = pre[3][nd_o][u_o];
      c_o = sigm(gf) * c_o + sigm(gi) * tanh_(gg);
      const float hv = sigm(go) * tanh_(c_o);
      const unsigned short hb = f2b(hv);
      hbuf[nb][0][nd_o][u_o] = hb;
      hbuf[nb][1][nd_o][u_o] = f2b(hv - b2f(hb));
    }
    __syncthreads();
  }

  U16x8 eah, eal;
  if (q < 2){
    const float* row = x + (long)(nb0 + n16) * 11;
    U16x8 H, L;
    #pragma unroll
    for (int j = 0; j < 8; j++){
      const int k = q * 8 + j;
      float v = (k < 11) ? row[k] : 0.f;
      unsigned short hb = f2b(v); H.u[j] = hb; L.u[j] = f2b(v - b2f(hb));
    }
    eah = H; eal = L;
  } else {
    const unsigned short* ph = &hbuf[0][0][n16][(q - 2) * 8];
    eah.v = *(const uint4*)ph;
    eal.v = *(const uint4*)(ph + 384);
  }

  bf16x8 ewf;
  {
    const int uo = wave * 16 + n16;
    const float* src = (q < 2) ? (Ws + uo * 11) : (Wn + uo * 11);
    const int kb = (q & 1) * 8;
    U16x8 a;
    #pragma unroll
    for (int j = 0; j < 8; j++){
      const int k = kb + j;
      a.u[j] = f2b((k < 11) ? src[k] : 0.f);
    }
    ewf = a.b;
  }

  {
    const int uo = wave * 16 + n16;
    const float bsv = bs[uo];
    f32x4 e = {bsv, bsv, bsv, bsv};
    e = __builtin_amdgcn_mfma_f32_16x16x32_bf16(eah.b, ewf, e, 0, 0, 0);
    e = __builtin_amdgcn_mfma_f32_16x16x32_bf16(eal.b, ewf, e, 0, 0, 0);
    #pragma unroll
    for (int r = 0; r < 4; r++){
      const float vv = fmaxf(e[r], 0.f);
      out_hl[(size_t)(nb0 + q * 4 + r) * 64 + uo] = f2b(vv);
    }
  }
}

// ---------------------------------------------------------------------------
// Layers 2/3/4: transposed MFMA (A=weights rows=units, B=[m;h] cols=nodes),
// bf16 hi-only activations. All 16 m-rows prefetched upfront into swizzled
// LDS (slot ^= nd+t) -> recurrence has zero global loads, 1 barrier/step,
// conflict-free b128. hbuf swizzle: slot (s+node)&7.
// mode 0: out_hl = relu(hself@WsT + bs + hK@WnT)  (u16 table)
// mode 1: out_f32[n] = hself@WsT + bs + hK@WnT (o=1)
// ---------------------------------------------------------------------------
__global__ __launch_bounds__(256, 4) void sage64_kernel(
    const unsigned short* __restrict__ in_hl, const int* __restrict__ nbr,
    const float* __restrict__ Wih, const float* __restrict__ Whh,
    const float* __restrict__ bih, const float* __restrict__ bhh,
    const float* __restrict__ Ws,  const float* __restrict__ bs,
    const float* __restrict__ Wn,
    unsigned short* __restrict__ out_hl, float* __restrict__ out_f32, int mode)
{
  __shared__ uint4 mbuf[16][16][8];   // [t][node][slot sw (s+nd+t)&7]  32 KB
  __shared__ uint4 hbuf[2][16][8];    // [buf][node][slot sw (s+n)&7]    4 KB

  const int tid = threadIdx.x;
  const int wv = tid >> 6, lane = tid & 63;
  const int n16 = lane & 15, q = lane >> 4;
  const int nb0 = blockIdx.x * 16;

  // prefetch all 16 messages per node: thread (nd, t) loads one 128B row
  {
    const int nd = tid >> 4, t = tid & 15;
    const int gn = nbr[(nb0 + nd) * 16 + t];
    const uint4* src = (const uint4*)(in_hl + (size_t)gn * 64);
    #pragma unroll
    for (int s = 0; s < 8; s++)
      mbuf[t][nd][(s + nd + t) & 7] = src[s];
  }
  // zero hbuf[0] (initial h): 2*16*8 uint4 -> first buffer only = 512 uints
  { unsigned int* p = (unsigned int*)&hbuf[0][0][0];
    for (int i = tid; i < 512; i += 256) p[i] = 0u; }

  // resident weight A-frags (hi only): gate g, kc; lane row = unit wv*16+n16
  bf16x8 wih_f[4][2], whh_f[4][2];
  #pragma unroll
  for (int g = 0; g < 4; g++){
    const int row = g * 64 + wv * 16 + n16;
    #pragma unroll
    for (int kc = 0; kc < 2; kc++){
      wih_f[g][kc] = load8_bf16(Wih + row * 64 + kc * 32 + q * 8);
      whh_f[g][kc] = load8_bf16(Whh + row * 64 + kc * 32 + q * 8);
    }
  }
  // biases for this lane's 4 units (rows q*4+r of tile wv), all 4 gates
  f32x4 bg[4];
  #pragma unroll
  for (int g = 0; g < 4; g++){
    float4 bi = *(const float4*)(bih + g * 64 + wv * 16 + q * 4);
    float4 bh = *(const float4*)(bhh + g * 64 + wv * 16 + q * 4);
    f32x4 s = {bi.x + bh.x, bi.y + bh.y, bi.z + bh.z, bi.w + bh.w};
    bg[g] = s;
  }

  float c4[4] = {0.f, 0.f, 0.f, 0.f};
  __syncthreads();

  for (int t = 0; t < 16; t++){
    const int db = t & 1, nbf = db ^ 1;

    // B-frags: lane (n16=node col, q=k-quad)
    bf16x8 mh[2], hh[2];
    #pragma unroll
    for (int kc = 0; kc < 2; kc++){
      U16x8 a; a.v = mbuf[t][n16][(kc * 4 + q + n16 + t) & 7]; mh[kc] = a.b;
      U16x8 c_; c_.v = hbuf[db][n16][(kc * 4 + q + n16) & 7];  hh[kc] = c_.b;
    }

    f32x4 acc[4];
    #pragma unroll
    for (int g = 0; g < 4; g++) acc[g] = bg[g];
    #pragma unroll
    for (int kc = 0; kc < 2; kc++){
      #pragma unroll
      for (int g = 0; g < 4; g++)
        acc[g] = __builtin_amdgcn_mfma_f32_16x16x32_bf16(wih_f[g][kc], mh[kc], acc[g], 0, 0, 0);
      #pragma unroll
      for (int g = 0; g < 4; g++)
        acc[g] = __builtin_amdgcn_mfma_f32_16x16x32_bf16(whh_f[g][kc], hh[kc], acc[g], 0, 0, 0);
    }

    // gates: lane (n16=node, q) holds i/f/g/o for units wv*16+q*4+r
    unsigned short hB[4];
    #pragma unroll
    for (int r = 0; r < 4; r++){
      const float iv = sigm(acc[0][r]);
      const float fv = sigm(acc[1][r]);
      const float gg = tanh_(acc[2][r]);
      const float ov = sigm(acc[3][r]);
      c4[r] = fv * c4[r] + iv * gg;
      hB[r] = f2b(ov * tanh_(c4[r]));
    }
    {
      const int idx = wv * 4 + q;            // uint2 index within node row
      const int slot = idx >> 1, half = idx & 1;
      ((uint2*)&hbuf[nbf][n16][(slot + n16) & 7])[half] =
          make_uint2((unsigned)hB[0] | ((unsigned)hB[1] << 16),
                     (unsigned)hB[2] | ((unsigned)hB[3] << 16));
    }
    __syncthreads();
  }

  // ---- epilogue: B = hself (global, hi) and hK (hbuf[0]) ----
  bf16x8 sH[2], kH[2];
  #pragma unroll
  for (int kc = 0; kc < 2; kc++){
    U16x8 a; a.v = *(const uint4*)(in_hl + (size_t)(nb0 + n16) * 64 + kc * 32 + q * 8);
    sH[kc] = a.b;
    U16x8 c_; c_.v = hbuf[0][n16][(kc * 4 + q + n16) & 7]; kH[kc] = c_.b;
  }

  if (mode == 0){
    bf16x8 ws_f[2], wn_f[2];
    #pragma unroll
    for (int kc = 0; kc < 2; kc++){
      ws_f[kc] = load8_bf16(Ws + (wv * 16 + n16) * 64 + kc * 32 + q * 8);
      wn_f[kc] = load8_bf16(Wn + (wv * 16 + n16) * 64 + kc * 32 + q * 8);
    }
    float4 bsv = *(const float4*)(bs + wv * 16 + q * 4);
    f32x4 e = {bsv.x, bsv.y, bsv.z, bsv.w};
    #pragma unroll
    for (int kc = 0; kc < 2; kc++){
      e = __builtin_amdgcn_mfma_f32_16x16x32_bf16(ws_f[kc], sH[kc], e, 0, 0, 0);
      e = __builtin_amdgcn_mfma_f32_16x16x32_bf16(wn_f[kc], kH[kc], e, 0, 0, 0);
    }
    unsigned short oB[4];
    #pragma unroll
    for (int r = 0; r < 4; r++) oB[r] = f2b(fmaxf(e[r], 0.f));
    *(uint2*)(out_hl + (size_t)(nb0 + n16) * 64 + wv * 16 + q * 4) =
        make_uint2((unsigned)oB[0] | ((unsigned)oB[1] << 16),
                   (unsigned)oB[2] | ((unsigned)oB[3] << 16));
  } else {
    if (wv == 0){
      bf16x8 ws_f[2], wn_f[2];
      #pragma unroll
      for (int kc = 0; kc < 2; kc++){
        U16x8 a, b_;
        a.v = make_uint4(0u,0u,0u,0u); b_.v = make_uint4(0u,0u,0u,0u);
        if (n16 == 0){
          a.b  = load8_bf16(Ws + kc * 32 + q * 8);
          b_.b = load8_bf16(Wn + kc * 32 + q * 8);
        }
        ws_f[kc] = a.b; wn_f[kc] = b_.b;
      }
      f32x4 e = {0.f, 0.f, 0.f, 0.f};
      #pragma unroll
      for (int kc = 0; kc < 2; kc++){
        e = __builtin_amdgcn_mfma_f32_16x16x32_bf16(ws_f[kc], sH[kc], e, 0, 0, 0);
        e = __builtin_amdgcn_mfma_f32_16x16x32_bf16(wn_f[kc], kH[kc], e, 0, 0, 0);
      }
      if (q == 0) out_f32[nb0 + n16] = e[0] + bs[0];
    }
  }
}

// ---------------------------------------------------------------------------
// GRU cell: h3 (u16 table) + prev (fp32) -> u16 table.
// A rows = nodes, B = weight rows (original orientation).
// ---------------------------------------------------------------------------
__global__ __launch_bounds__(256) void gru_kernel(
    const unsigned short* __restrict__ h3_hl, const float* __restrict__ prev,
    const float* __restrict__ gWih, const float* __restrict__ gWhh,
    const float* __restrict__ gbih, const float* __restrict__ gbhh,
    unsigned short* __restrict__ out_hl)
{
  const int tid = threadIdx.x, wave = tid >> 6, lane = tid & 63;
  const int n16 = lane & 15, q = lane >> 4;
  const int nb0 = blockIdx.x * 16;
  const int u_ = wave * 16 + n16;

  bf16x8 ah[2], ap[2];
  #pragma unroll
  for (int kc = 0; kc < 2; kc++){
    U16x8 a; a.v = *(const uint4*)(h3_hl + (size_t)(nb0 + n16) * 64 + kc * 32 + q * 8);
    ah[kc] = a.b;
    ap[kc] = load8_bf16(prev + (size_t)(nb0 + n16) * 64 + kc * 32 + q * 8);
  }

  bf16x8 wi_f[3][2], wh_f[3][2];
  #pragma unroll
  for (int g = 0; g < 3; g++){
    const int row = g * 64 + wave * 16 + n16;
    #pragma unroll
    for (int kc = 0; kc < 2; kc++){
      wi_f[g][kc] = load8_bf16(gWih + row * 64 + kc * 32 + q * 8);
      wh_f[g][kc] = load8_bf16(gWhh + row * 64 + kc * 32 + q * 8);
    }
  }

  f32x4 gi[3], gh[3];
  #pragma unroll
  for (int g = 0; g < 3; g++){
    const float bi = gbih[g * 64 + u_], bh = gbhh[g * 64 + u_];
    f32x4 vi = {bi, bi, bi, bi}; gi[g] = vi;
    f32x4 vh = {bh, bh, bh, bh}; gh[g] = vh;
  }
  #pragma unroll
  for (int kc = 0; kc < 2; kc++){
    #pragma unroll
    for (int g = 0; g < 3; g++)
      gi[g] = __builtin_amdgcn_mfma_f32_16x16x32_bf16(ah[kc], wi_f[g][kc], gi[g], 0, 0, 0);
    #pragma unroll
    for (int g = 0; g < 3; g++)
      gh[g] = __builtin_amdgcn_mfma_f32_16x16x32_bf16(ap[kc], wh_f[g][kc], gh[g], 0, 0, 0);
  }

  #pragma unroll
  for (int r = 0; r < 4; r++){
    const long node = nb0 + q * 4 + r;
    const float rv = sigm(gi[0][r] + gh[0][r]);
    const float zv = sigm(gi[1][r] + gh[1][r]);
    const float nv = tanh_(gi[2][r] + rv * gh[2][r]);
    const float hp = prev[node * 64 + u_];
    const float v = (1.f - zv) * nv + zv * hp;
    out_hl[(size_t)node * 64 + u_] = f2b(v);
  }
}

// ---------------------------------------------------------------------------
extern "C" void kernel_launch(void* const* d_in, const int* in_sizes, int n_in,
                              void* d_out, int out_size, void* d_ws, size_t ws_size,
                              hipStream_t stream)
{
  (void)in_sizes; (void)n_in; (void)out_size; (void)ws_size;
  const float* x    = (const float*)d_in[0];
  const int*   nbr  = (const int*)d_in[1];
  const float* prev = (const float*)d_in[2];
  auto W = [&](int i){ return (const float*)d_in[i]; };

  unsigned short* tabA = (unsigned short*)d_ws;            // [N][64] u16, 6.4 MB
  unsigned short* tabB = tabA + (size_t)N_NODES * 64;      // second table

  // layer 1 (d=11): x -> tabA (=h1)
  l1_kernel<<<N_NODES / 16, 256, 0, stream>>>(
      x, nbr, W(3), W(4), W(5), W(6), W(7), W(8), W(9), tabA);
  // layer 2: tabA -> tabB
  sage64_kernel<<<N_NODES / 16, 256, 0, stream>>>(
      tabA, nbr, W(10), W(11), W(12), W(13), W(14), W(15), W(16), tabB, nullptr, 0);
  // layer 3: tabB -> tabA
  sage64_kernel<<<N_NODES / 16, 256, 0, stream>>>(
      tabB, nbr, W(17), W(18), W(19), W(20), W(21), W(22), W(23), tabA, nullptr, 0);
  // GRU: (h3=tabA, prev) -> tabB
  gru_kernel<<<N_NODES / 16, 256, 0, stream>>>(
      tabA, prev, W(31), W(32), W(33), W(34), tabB);
  // layer 4 (o=1): tabB -> d_out (fp32 logits)
  sage64_kernel<<<N_NODES / 16, 256, 0, stream>>>(
      tabB, nbr, W(24), W(25), W(26), W(27), W(28), W(29), W(30),
      nullptr, (float*)d_out, 1);
}

// Round 6
// 503.714 us; speedup vs baseline: 3.5055x; 1.1747x over previous
//
#include <hip/hip_runtime.h>

#define N_NODES 50000

typedef __bf16 bf16x8 __attribute__((ext_vector_type(8)));
typedef float f32x4 __attribute__((ext_vector_type(4)));

union U16x8 { uint4 v; unsigned short u[8]; bf16x8 b; };

__device__ __forceinline__ float b2f(unsigned short h){
  unsigned int u = ((unsigned int)h) << 16;
  return __builtin_bit_cast(float, u);
}
__device__ __forceinline__ unsigned short f2b(float x){
  unsigned int u = __builtin_bit_cast(unsigned int, x);
  u = u + 0x7FFFu + ((u >> 16) & 1u);
  return (unsigned short)(u >> 16);
}
// raw-hardware sigmoid/tanh: v_exp_f32 + v_rcp_f32, no division refinement.
__device__ __forceinline__ float sigm(float x){
  const float e = __builtin_amdgcn_exp2f(x * -1.4426950408889634f);
  return __builtin_amdgcn_rcpf(1.0f + e);
}
__device__ __forceinline__ float tanh_(float x){
  const float e = __builtin_amdgcn_exp2f(x * 2.8853900817779268f);
  return fmaf(-2.0f, __builtin_amdgcn_rcpf(1.0f + e), 1.0f);
}

// 8 consecutive f32 -> bf16x8 (RNE), hi only
__device__ __forceinline__ bf16x8 load8_bf16(const float* p){
  float4 a = *(const float4*)p; float4 c = *(const float4*)(p + 4);
  U16x8 r;
  r.u[0]=f2b(a.x); r.u[1]=f2b(a.y); r.u[2]=f2b(a.z); r.u[3]=f2b(a.w);
  r.u[4]=f2b(c.x); r.u[5]=f2b(c.y); r.u[6]=f2b(c.z); r.u[7]=f2b(c.w);
  return r.b;
}

// ---------------------------------------------------------------------------
// Activation tables (all inter-layer tensors): u16[node][64], bf16 hi of fp32.
// ---------------------------------------------------------------------------

// ---------------------------------------------------------------------------
// Layer 1 (d=11) via MFMA, single barrier per step.
// A = [m;h] (rows=nodes, hi/lo), B = combined [Wih|Whh] gate tile.
// Every wave issues all 4 gate MFMAs (duplicated across waves); wave w keeps
// only C-rows r==w -> lane-local LSTM update for (node q*4+w, unit n16).
// All 16 neighbor rows prefetched upfront. Epilogue -> u16 hi table.
// ---------------------------------------------------------------------------
__global__ __launch_bounds__(256) void l1_kernel(
    const float* __restrict__ x, const int* __restrict__ nbr,
    const float* __restrict__ Wih, const float* __restrict__ Whh,
    const float* __restrict__ bih, const float* __restrict__ bhh,
    const float* __restrict__ Ws,  const float* __restrict__ bs,
    const float* __restrict__ Wn,  unsigned short* __restrict__ out_hl)
{
  __shared__ unsigned short mbuf[16][2][16][24];  // [t][hl][node][k] 24.6 KB
  __shared__ unsigned short hbuf[2][2][16][24];   // [buf][hl][node][unit] 3 KB

  const int tid  = threadIdx.x;
  const int wave = tid >> 6, lane = tid & 63;
  const int n16  = lane & 15, q = lane >> 4;
  const int nb0  = blockIdx.x * 16;

  // zero hbuf (both buffers incl. unit pads)
  { unsigned int* p = (unsigned int*)hbuf;
    for (int i = tid; i < 768; i += 256) p[i] = 0u; }

  // prefetch all 16x16 neighbor rows, hi/lo split
  {
    const int nd = tid >> 4, t = tid & 15;
    const int gn = nbr[(nb0 + nd) * 16 + t];
    const float* row = x + (long)gn * 11;
    float v[16];
    #pragma unroll
    for (int j = 0; j < 11; j++) v[j] = row[j];
    #pragma unroll
    for (int j = 11; j < 16; j++) v[j] = 0.f;
    #pragma unroll
    for (int j = 0; j < 16; j++){
      unsigned short hb = f2b(v[j]);
      mbuf[t][0][nd][j] = hb;
      mbuf[t][1][nd][j] = f2b(v[j] - b2f(hb));
    }
  }

  // B-frags for ALL 4 gates: lane (n16=unit, q): k=q*8+j;
  // q<2 -> Wih[g*11+u][k], q>=2 -> Whh[g*11+u][k-16]
  bf16x8 wf[4];
  float bg4[4];
  #pragma unroll
  for (int g = 0; g < 4; g++){
    const int u = n16;
    const float* src = (q < 2) ? (Wih + (g * 11 + u) * 11)
                               : (Whh + (g * 11 + u) * 11);
    const int kb = (q & 1) * 8;
    U16x8 a;
    #pragma unroll
    for (int j = 0; j < 8; j++){
      const int k = kb + j;
      float v = (u < 11 && k < 11) ? src[k] : 0.f;
      a.u[j] = f2b(v);
    }
    wf[g] = a.b;
    bg4[g] = (n16 < 11) ? (bih[g * 11 + n16] + bhh[g * 11 + n16]) : 0.f;
  }

  float c_ = 0.f;   // cell state for (node q*4+wave, unit n16)
  __syncthreads();

  for (int t = 0; t < 16; t++){
    const int db = t & 1, nb = db ^ 1;

    // A-frag hi/lo: rows = nodes (n16); q<2 from mbuf[t], q>=2 from hbuf[db]
    const unsigned short* ph = (q < 2) ? &mbuf[t][0][n16][q * 8]
                                       : &hbuf[db][0][n16][(q - 2) * 8];
    U16x8 ah, al;
    ah.v = *(const uint4*)ph;
    al.v = *(const uint4*)(ph + 384);

    f32x4 acc[4];
    #pragma unroll
    for (int g = 0; g < 4; g++){
      f32x4 av = {bg4[g], bg4[g], bg4[g], bg4[g]};
      acc[g] = __builtin_amdgcn_mfma_f32_16x16x32_bf16(ah.b, wf[g], av, 0, 0, 0);
      acc[g] = __builtin_amdgcn_mfma_f32_16x16x32_bf16(al.b, wf[g], acc[g], 0, 0, 0);
    }

    // keep only row r == wave: C row=q*4+r -> node, col=n16 -> unit
    {
      const int r = wave;
      const float iv = sigm(acc[0][r]);
      const float fv = sigm(acc[1][r]);
      const float gg = tanh_(acc[2][r]);
      const float ov = sigm(acc[3][r]);
      c_ = fv * c_ + iv * gg;
      const float hv = ov * tanh_(c_);
      const unsigned short hb = f2b(hv);
      hbuf[nb][0][q * 4 + wave][n16] = hb;
      hbuf[nb][1][q * 4 + wave][n16] = f2b(hv - b2f(hb));
    }
    __syncthreads();
  }

  // ---- epilogue: out[node][uo] = relu(x_self@WsT + bs + hK@WnT) ----
  U16x8 eah, eal;
  if (q < 2){
    const float* row = x + (long)(nb0 + n16) * 11;
    U16x8 H, L;
    #pragma unroll
    for (int j = 0; j < 8; j++){
      const int k = q * 8 + j;
      float v = (k < 11) ? row[k] : 0.f;
      unsigned short hb = f2b(v); H.u[j] = hb; L.u[j] = f2b(v - b2f(hb));
    }
    eah = H; eal = L;
  } else {
    const unsigned short* ph = &hbuf[0][0][n16][(q - 2) * 8];
    eah.v = *(const uint4*)ph;
    eal.v = *(const uint4*)(ph + 384);
  }

  bf16x8 ewf;
  {
    const int uo = wave * 16 + n16;
    const float* src = (q < 2) ? (Ws + uo * 11) : (Wn + uo * 11);
    const int kb = (q & 1) * 8;
    U16x8 a;
    #pragma unroll
    for (int j = 0; j < 8; j++){
      const int k = kb + j;
      a.u[j] = f2b((k < 11) ? src[k] : 0.f);
    }
    ewf = a.b;
  }

  {
    const int uo = wave * 16 + n16;
    const float bsv = bs[uo];
    f32x4 e = {bsv, bsv, bsv, bsv};
    e = __builtin_amdgcn_mfma_f32_16x16x32_bf16(eah.b, ewf, e, 0, 0, 0);
    e = __builtin_amdgcn_mfma_f32_16x16x32_bf16(eal.b, ewf, e, 0, 0, 0);
    #pragma unroll
    for (int r = 0; r < 4; r++){
      const float vv = fmaxf(e[r], 0.f);
      out_hl[(size_t)(nb0 + q * 4 + r) * 64 + uo] = f2b(vv);
    }
  }
}

// ---------------------------------------------------------------------------
// Layers 2/3/4: transposed MFMA (A=weights rows=units, B=[m;h] cols=nodes),
// bf16 hi-only activations, upfront m-prefetch, swizzled LDS.
// __launch_bounds__(256,3): the (256,4) variant forced VGPR=64 and spilled
// (WRITE_SIZE 137 MB); 3 gives the allocator the 84-VGPR no-spill config.
// ---------------------------------------------------------------------------
__global__ __launch_bounds__(256, 3) void sage64_kernel(
    const unsigned short* __restrict__ in_hl, const int* __restrict__ nbr,
    const float* __restrict__ Wih, const float* __restrict__ Whh,
    const float* __restrict__ bih, const float* __restrict__ bhh,
    const float* __restrict__ Ws,  const float* __restrict__ bs,
    const float* __restrict__ Wn,
    unsigned short* __restrict__ out_hl, float* __restrict__ out_f32, int mode)
{
  __shared__ uint4 mbuf[16][16][8];   // [t][node][slot sw (s+nd+t)&7]  32 KB
  __shared__ uint4 hbuf[2][16][8];    // [buf][node][slot sw (s+n)&7]    4 KB

  const int tid = threadIdx.x;
  const int wv = tid >> 6, lane = tid & 63;
  const int n16 = lane & 15, q = lane >> 4;
  const int nb0 = blockIdx.x * 16;

  // prefetch all 16 messages per node: thread (nd, t) loads one 128B row
  {
    const int nd = tid >> 4, t = tid & 15;
    const int gn = nbr[(nb0 + nd) * 16 + t];
    const uint4* src = (const uint4*)(in_hl + (size_t)gn * 64);
    #pragma unroll
    for (int s = 0; s < 8; s++)
      mbuf[t][nd][(s + nd + t) & 7] = src[s];
  }
  // zero hbuf[0] (initial h)
  { unsigned int* p = (unsigned int*)&hbuf[0][0][0];
    for (int i = tid; i < 512; i += 256) p[i] = 0u; }

  // resident weight A-frags (hi only): gate g, kc; lane row = unit wv*16+n16
  bf16x8 wih_f[4][2], whh_f[4][2];
  #pragma unroll
  for (int g = 0; g < 4; g++){
    const int row = g * 64 + wv * 16 + n16;
    #pragma unroll
    for (int kc = 0; kc < 2; kc++){
      wih_f[g][kc] = load8_bf16(Wih + row * 64 + kc * 32 + q * 8);
      whh_f[g][kc] = load8_bf16(Whh + row * 64 + kc * 32 + q * 8);
    }
  }
  // biases for this lane's 4 units (rows q*4+r of tile wv), all 4 gates
  f32x4 bg[4];
  #pragma unroll
  for (int g = 0; g < 4; g++){
    float4 bi = *(const float4*)(bih + g * 64 + wv * 16 + q * 4);
    float4 bh = *(const float4*)(bhh + g * 64 + wv * 16 + q * 4);
    f32x4 s = {bi.x + bh.x, bi.y + bh.y, bi.z + bh.z, bi.w + bh.w};
    bg[g] = s;
  }

  float c4[4] = {0.f, 0.f, 0.f, 0.f};
  __syncthreads();

  for (int t = 0; t < 16; t++){
    const int db = t & 1, nbf = db ^ 1;

    // B-frags: lane (n16=node col, q=k-quad)
    bf16x8 mh[2], hh[2];
    #pragma unroll
    for (int kc = 0; kc < 2; kc++){
      U16x8 a; a.v = mbuf[t][n16][(kc * 4 + q + n16 + t) & 7]; mh[kc] = a.b;
      U16x8 c_; c_.v = hbuf[db][n16][(kc * 4 + q + n16) & 7];  hh[kc] = c_.b;
    }

    f32x4 acc[4];
    #pragma unroll
    for (int g = 0; g < 4; g++) acc[g] = bg[g];
    #pragma unroll
    for (int kc = 0; kc < 2; kc++){
      #pragma unroll
      for (int g = 0; g < 4; g++)
        acc[g] = __builtin_amdgcn_mfma_f32_16x16x32_bf16(wih_f[g][kc], mh[kc], acc[g], 0, 0, 0);
      #pragma unroll
      for (int g = 0; g < 4; g++)
        acc[g] = __builtin_amdgcn_mfma_f32_16x16x32_bf16(whh_f[g][kc], hh[kc], acc[g], 0, 0, 0);
    }

    // gates: lane (n16=node, q) holds i/f/g/o for units wv*16+q*4+r
    unsigned short hB[4];
    #pragma unroll
    for (int r = 0; r < 4; r++){
      const float iv = sigm(acc[0][r]);
      const float fv = sigm(acc[1][r]);
      const float gg = tanh_(acc[2][r]);
      const float ov = sigm(acc[3][r]);
      c4[r] = fv * c4[r] + iv * gg;
      hB[r] = f2b(ov * tanh_(c4[r]));
    }
    {
      const int idx = wv * 4 + q;            // uint2 index within node row
      const int slot = idx >> 1, half = idx & 1;
      ((uint2*)&hbuf[nbf][n16][(slot + n16) & 7])[half] =
          make_uint2((unsigned)hB[0] | ((unsigned)hB[1] << 16),
                     (unsigned)hB[2] | ((unsigned)hB[3] << 16));
    }
    __syncthreads();
  }

  // ---- epilogue: B = hself (global, hi) and hK (hbuf[0]) ----
  bf16x8 sH[2], kH[2];
  #pragma unroll
  for (int kc = 0; kc < 2; kc++){
    U16x8 a; a.v = *(const uint4*)(in_hl + (size_t)(nb0 + n16) * 64 + kc * 32 + q * 8);
    sH[kc] = a.b;
    U16x8 c_; c_.v = hbuf[0][n16][(kc * 4 + q + n16) & 7]; kH[kc] = c_.b;
  }

  if (mode == 0){
    bf16x8 ws_f[2], wn_f[2];
    #pragma unroll
    for (int kc = 0; kc < 2; kc++){
      ws_f[kc] = load8_bf16(Ws + (wv * 16 + n16) * 64 + kc * 32 + q * 8);
      wn_f[kc] = load8_bf16(Wn + (wv * 16 + n16) * 64 + kc * 32 + q * 8);
    }
    float4 bsv = *(const float4*)(bs + wv * 16 + q * 4);
    f32x4 e = {bsv.x, bsv.y, bsv.z, bsv.w};
    #pragma unroll
    for (int kc = 0; kc < 2; kc++){
      e = __builtin_amdgcn_mfma_f32_16x16x32_bf16(ws_f[kc], sH[kc], e, 0, 0, 0);
      e = __builtin_amdgcn_mfma_f32_16x16x32_bf16(wn_f[kc], kH[kc], e, 0, 0, 0);
    }
    unsigned short oB[4];
    #pragma unroll
    for (int r = 0; r < 4; r++) oB[r] = f2b(fmaxf(e[r], 0.f));
    *(uint2*)(out_hl + (size_t)(nb0 + n16) * 64 + wv * 16 + q * 4) =
        make_uint2((unsigned)oB[0] | ((unsigned)oB[1] << 16),
                   (unsigned)oB[2] | ((unsigned)oB[3] << 16));
  } else {
    if (wv == 0){
      bf16x8 ws_f[2], wn_f[2];
      #pragma unroll
      for (int kc = 0; kc < 2; kc++){
        U16x8 a, b_;
        a.v = make_uint4(0u,0u,0u,0u); b_.v = make_uint4(0u,0u,0u,0u);
        if (n16 == 0){
          a.b  = load8_bf16(Ws + kc * 32 + q * 8);
          b_.b = load8_bf16(Wn + kc * 32 + q * 8);
        }
        ws_f[kc] = a.b; wn_f[kc] = b_.b;
      }
      f32x4 e = {0.f, 0.f, 0.f, 0.f};
      #pragma unroll
      for (int kc = 0; kc < 2; kc++){
        e = __builtin_amdgcn_mfma_f32_16x16x32_bf16(ws_f[kc], sH[kc], e, 0, 0, 0);
        e = __builtin_amdgcn_mfma_f32_16x16x32_bf16(wn_f[kc], kH[kc], e, 0, 0, 0);
      }
      if (q == 0) out_f32[nb0 + n16] = e[0] + bs[0];
    }
  }
}

// ---------------------------------------------------------------------------
// GRU cell: h3 (u16 table) + prev (fp32) -> u16 table.
// ---------------------------------------------------------------------------
__global__ __launch_bounds__(256) void gru_kernel(
    const unsigned short* __restrict__ h3_hl, const float* __restrict__ prev,
    const float* __restrict__ gWih, const float* __restrict__ gWhh,
    const float* __restrict__ gbih, const float* __restrict__ gbhh,
    unsigned short* __restrict__ out_hl)
{
  const int tid = threadIdx.x, wave = tid >> 6, lane = tid & 63;
  const int n16 = lane & 15, q = lane >> 4;
  const int nb0 = blockIdx.x * 16;
  const int u_ = wave * 16 + n16;

  bf16x8 ah[2], ap[2];
  #pragma unroll
  for (int kc = 0; kc < 2; kc++){
    U16x8 a; a.v = *(const uint4*)(h3_hl + (size_t)(nb0 + n16) * 64 + kc * 32 + q * 8);
    ah[kc] = a.b;
    ap[kc] = load8_bf16(prev + (size_t)(nb0 + n16) * 64 + kc * 32 + q * 8);
  }

  bf16x8 wi_f[3][2], wh_f[3][2];
  #pragma unroll
  for (int g = 0; g < 3; g++){
    const int row = g * 64 + wave * 16 + n16;
    #pragma unroll
    for (int kc = 0; kc < 2; kc++){
      wi_f[g][kc] = load8_bf16(gWih + row * 64 + kc * 32 + q * 8);
      wh_f[g][kc] = load8_bf16(gWhh + row * 64 + kc * 32 + q * 8);
    }
  }

  f32x4 gi[3], gh[3];
  #pragma unroll
  for (int g = 0; g < 3; g++){
    const float bi = gbih[g * 64 + u_], bh = gbhh[g * 64 + u_];
    f32x4 vi = {bi, bi, bi, bi}; gi[g] = vi;
    f32x4 vh = {bh, bh, bh, bh}; gh[g] = vh;
  }
  #pragma unroll
  for (int kc = 0; kc < 2; kc++){
    #pragma unroll
    for (int g = 0; g < 3; g++)
      gi[g] = __builtin_amdgcn_mfma_f32_16x16x32_bf16(ah[kc], wi_f[g][kc], gi[g], 0, 0, 0);
    #pragma unroll
    for (int g = 0; g < 3; g++)
      gh[g] = __builtin_amdgcn_mfma_f32_16x16x32_bf16(ap[kc], wh_f[g][kc], gh[g], 0, 0, 0);
  }

  #pragma unroll
  for (int r = 0; r < 4; r++){
    const long node = nb0 + q * 4 + r;
    const float rv = sigm(gi[0][r] + gh[0][r]);
    const float zv = sigm(gi[1][r] + gh[1][r]);
    const float nv = tanh_(gi[2][r] + rv * gh[2][r]);
    const float hp = prev[node * 64 + u_];
    const float v = (1.f - zv) * nv + zv * hp;
    out_hl[(size_t)node * 64 + u_] = f2b(v);
  }
}

// ---------------------------------------------------------------------------
extern "C" void kernel_launch(void* const* d_in, const int* in_sizes, int n_in,
                              void* d_out, int out_size, void* d_ws, size_t ws_size,
                              hipStream_t stream)
{
  (void)in_sizes; (void)n_in; (void)out_size; (void)ws_size;
  const float* x    = (const float*)d_in[0];
  const int*   nbr  = (const int*)d_in[1];
  const float* prev = (const float*)d_in[2];
  auto W = [&](int i){ return (const float*)d_in[i]; };

  unsigned short* tabA = (unsigned short*)d_ws;            // [N][64] u16, 6.4 MB
  unsigned short* tabB = tabA + (size_t)N_NODES * 64;      // second table

  // layer 1 (d=11): x -> tabA (=h1)
  l1_kernel<<<N_NODES / 16, 256, 0, stream>>>(
      x, nbr, W(3), W(4), W(5), W(6), W(7), W(8), W(9), tabA);
  // layer 2: tabA -> tabB
  sage64_kernel<<<N_NODES / 16, 256, 0, stream>>>(
      tabA, nbr, W(10), W(11), W(12), W(13), W(14), W(15), W(16), tabB, nullptr, 0);
  // layer 3: tabB -> tabA
  sage64_kernel<<<N_NODES / 16, 256, 0, stream>>>(
      tabB, nbr, W(17), W(18), W(19), W(20), W(21), W(22), W(23), tabA, nullptr, 0);
  // GRU: (h3=tabA, prev) -> tabB
  gru_kernel<<<N_NODES / 16, 256, 0, stream>>>(
      tabA, prev, W(31), W(32), W(33), W(34), tabB);
  // layer 4 (o=1): tabB -> d_out (fp32 logits)
  sage64_kernel<<<N_NODES / 16, 256, 0, stream>>>(
      tabB, nbr, W(24), W(25), W(26), W(27), W(28), W(29), W(30),
      nullptr, (float*)d_out, 1);
}